// Round 6
// baseline (160.942 us; speedup 1.0000x reference)
//
#include <hip/hip_runtime.h>
#include <hip/hip_bf16.h>

#define LEAKY(v) ((v) > 0.0f ? (v) : 0.01f * (v))

constexpr int B_   = 1024;
constexpr int PAD  = 30;
constexpr int E    = 512;
constexpr int IMG  = 2048;
constexpr int C1   = 200;
constexpr int C2   = 300;
constexpr int C3   = 300;
constexpr int LIN2 = 400;

constexpr int NT1P = 16, KT1 = 48;   // conv1: 256-pad x 1536
constexpr int NT2P = 20, KT2 = 21;   // conv2: 320-pad x (3x7 steps in 256-pad rows)
constexpr int NT3P = 20, KT3 = 30;   // conv3: 320-pad x (3x10 steps in 320-pad rows)
constexpr int NTMP = 28, KTM = 83;   // final: 448-pad x 2656
constexpr int FK  = 2656;            // feats K padded (2648 -> 2656)

constexpr int T1 = NT1P * KT1;       // 768
constexpr int T2 = NT2P * KT2;       // 420
constexpr int T3 = NT3P * KT3;       // 600
constexpr int TM = NTMP * KTM;       // 2324
constexpr int TTOT = T1 + T2 + T3 + TM;  // 4112

typedef __attribute__((ext_vector_type(8))) short bf16x8;
typedef __attribute__((ext_vector_type(4))) float f32x4;

__device__ inline unsigned short f2bf(float f) {
    __hip_bfloat16 h = __float2bfloat16(f);
    return *reinterpret_cast<unsigned short*>(&h);
}
__device__ inline float bf2f(unsigned short u) {
    unsigned int b = ((unsigned int)u) << 16;
    return __uint_as_float(b);
}

// ================= fused weight converter: fp32 -> bf16 fragments [nt][kk][lane][8]
__global__ __launch_bounds__(256) void convert_all(
    const float* __restrict__ W1, const float* __restrict__ W2,
    const float* __restrict__ W3, const float* __restrict__ Wm,
    unsigned short* __restrict__ W1t, unsigned short* __restrict__ W2t,
    unsigned short* __restrict__ W3t, unsigned short* __restrict__ Wmt)
{
    int idx = blockIdx.x * 256 + threadIdx.x;
    if (idx >= TTOT * 64) return;
    int lane = idx & 63, t = idx >> 6;
    unsigned short v[8];

    if (t < T1) {
        int kk = t % KT1, nt = t / KT1;
        int ch = nt * 16 + (lane & 15);
        int k0 = kk * 32 + (lane >> 4) * 8;
        #pragma unroll
        for (int j = 0; j < 8; ++j)
            v[j] = (ch < C1) ? f2bf(W1[(size_t)ch * (3*E) + k0 + j]) : (unsigned short)0;
        ushort4* dst = reinterpret_cast<ushort4*>(W1t) + (size_t)t * 128 + lane * 2;
        dst[0] = ushort4{v[0],v[1],v[2],v[3]};
        dst[1] = ushort4{v[4],v[5],v[6],v[7]};
    } else if (t < T1 + T2) {
        int tt = t - T1;
        int kk = tt % KT2, nt = tt / KT2;
        int ch = nt * 16 + (lane & 15);
        int rowoff = kk / 7;
        int cbase  = (kk % 7) * 32 + (lane >> 4) * 8;
        #pragma unroll
        for (int j = 0; j < 8; ++j) {
            int c = cbase + j;
            v[j] = (ch < C2 && c < C1) ? f2bf(W2[(size_t)ch * (3*C1) + rowoff * C1 + c])
                                       : (unsigned short)0;
        }
        ushort4* dst = reinterpret_cast<ushort4*>(W2t) + (size_t)tt * 128 + lane * 2;
        dst[0] = ushort4{v[0],v[1],v[2],v[3]};
        dst[1] = ushort4{v[4],v[5],v[6],v[7]};
    } else if (t < T1 + T2 + T3) {
        int tt = t - T1 - T2;
        int kk = tt % KT3, nt = tt / KT3;
        int ch = nt * 16 + (lane & 15);
        int rowoff = kk / 10;
        int cbase  = (kk % 10) * 32 + (lane >> 4) * 8;
        #pragma unroll
        for (int j = 0; j < 8; ++j) {
            int c = cbase + j;
            v[j] = (ch < C3 && c < C2) ? f2bf(W3[(size_t)ch * (3*C2) + rowoff * C2 + c])
                                       : (unsigned short)0;
        }
        ushort4* dst = reinterpret_cast<ushort4*>(W3t) + (size_t)tt * 128 + lane * 2;
        dst[0] = ushort4{v[0],v[1],v[2],v[3]};
        dst[1] = ushort4{v[4],v[5],v[6],v[7]};
    } else {
        int tt = t - T1 - T2 - T3;
        int kk = tt % KTM, nt = tt / KTM;
        int ch = nt * 16 + (lane & 15);
        int kbase = kk * 32 + (lane >> 4) * 8;
        #pragma unroll
        for (int j = 0; j < 8; ++j) {
            int k = kbase + j;
            v[j] = (ch < LIN2 && k < 2648) ? f2bf(Wm[(size_t)ch * 2648 + k])
                                           : (unsigned short)0;
        }
        ushort4* dst = reinterpret_cast<ushort4*>(Wmt) + (size_t)tt * 128 + lane * 2;
        dst[0] = ushort4{v[0],v[1],v[2],v[3]};
        dst[1] = ushort4{v[4],v[5],v[6],v[7]};
    }
}

// ================= conv1: 2 batches/block, wave = 4 nt x 4 M-tiles ==============
// LDS A: 66 rows x 512 bf16 swizzled. B-streams software-pipelined (distance 1).
__global__ __launch_bounds__(256, 2) void conv1_mfma(
    const int* __restrict__ sent, const float* __restrict__ emb,
    const unsigned short* __restrict__ W1t, const float* __restrict__ bias,
    float* __restrict__ y)
{
    const int blk = blockIdx.x;            // batches 2*blk, 2*blk+1
    const int tid = threadIdx.x;
    __shared__ unsigned short xs[66 * 512];
    __shared__ float rs[64];
    char* xsb = reinterpret_cast<char*>(xs);

    for (int idx = tid; idx < 60 * 128; idx += 256) {
        int rg = idx >> 7, c4 = idx & 127;
        int bl = rg / 30, r = rg % 30;
        int R = bl * 32 + r;
        int row = sent[(2 * blk + bl) * PAD + r];
        float4 v = reinterpret_cast<const float4*>(emb + (size_t)row * E)[c4];
        ushort4 h = {f2bf(v.x), f2bf(v.y), f2bf(v.z), f2bf(v.w)};
        int chunk = c4 >> 1, half = c4 & 1;
        *reinterpret_cast<ushort4*>(
            xsb + R * 1024 + ((chunk ^ (R & 7)) << 4) + half * 8) = h;
    }
    for (int idx = tid; idx < 6 * 128; idx += 256) {
        int zi = idx >> 7, c4 = idx & 127;
        int R = (zi < 2) ? (30 + zi) : (60 + zi);
        int chunk = c4 >> 1, half = c4 & 1;
        *reinterpret_cast<ushort4*>(
            xsb + R * 1024 + ((chunk ^ (R & 7)) << 4) + half * 8) = ushort4{0,0,0,0};
    }
    __syncthreads();

    const int wid = tid >> 6, lane = tid & 63;

    for (int r = wid; r < 64; r += 4) {
        float s = 0.f;
        #pragma unroll
        for (int j = 0; j < 8; ++j) {
            int e = lane + 64 * j;
            int chunk = e >> 3, within = e & 7;
            s += bf2f(*reinterpret_cast<unsigned short*>(
                xsb + r * 1024 + ((chunk ^ (r & 7)) << 4) + within * 2));
        }
        for (int off = 32; off; off >>= 1) s += __shfl_down(s, off);
        if (lane == 0) rs[r] = s;
    }
    __syncthreads();

    const int kg = lane >> 4, trow = lane & 15, g = kg;

    const bf16x8* wb = reinterpret_cast<const bf16x8*>(W1t);
    const bf16x8* wp0 = wb + (size_t)((wid     ) * KT1) * 64 + lane;
    const bf16x8* wp1 = wb + (size_t)((wid +  4) * KT1) * 64 + lane;
    const bf16x8* wp2 = wb + (size_t)((wid +  8) * KT1) * 64 + lane;
    const bf16x8* wp3 = wb + (size_t)((wid + 12) * KT1) * 64 + lane;

    // c<nt><mt>
    f32x4 c00={0,0,0,0},c01={0,0,0,0},c02={0,0,0,0},c03={0,0,0,0};
    f32x4 c10={0,0,0,0},c11={0,0,0,0},c12={0,0,0,0},c13={0,0,0,0};
    f32x4 c20={0,0,0,0},c21={0,0,0,0},c22={0,0,0,0},c23={0,0,0,0};
    f32x4 c30={0,0,0,0},c31={0,0,0,0},c32={0,0,0,0},c33={0,0,0,0};

#define ALOAD1(KK, A0, A1, A2, A3) do {                                          \
    int chunk_  = ((KK) & 15) * 4 + kg;                                          \
    int rowoff_ = (KK) >> 4;                                                     \
    int R0_ = trow + rowoff_;                                                    \
    int R1_ = R0_ + 16, R2_ = R0_ + 32, R3_ = R0_ + 48;                          \
    A0 = *reinterpret_cast<const bf16x8*>(xsb + R0_*1024 + ((chunk_ ^ (R0_ & 7)) << 4)); \
    A1 = *reinterpret_cast<const bf16x8*>(xsb + R1_*1024 + ((chunk_ ^ (R1_ & 7)) << 4)); \
    A2 = *reinterpret_cast<const bf16x8*>(xsb + R2_*1024 + ((chunk_ ^ (R2_ & 7)) << 4)); \
    A3 = *reinterpret_cast<const bf16x8*>(xsb + R3_*1024 + ((chunk_ ^ (R3_ & 7)) << 4)); \
} while (0)

#define MFMA16(A0, A1, A2, A3, B0, B1, B2, B3) do {                              \
    c00 = __builtin_amdgcn_mfma_f32_16x16x32_bf16(A0, B0, c00, 0, 0, 0);         \
    c01 = __builtin_amdgcn_mfma_f32_16x16x32_bf16(A1, B0, c01, 0, 0, 0);         \
    c02 = __builtin_amdgcn_mfma_f32_16x16x32_bf16(A2, B0, c02, 0, 0, 0);         \
    c03 = __builtin_amdgcn_mfma_f32_16x16x32_bf16(A3, B0, c03, 0, 0, 0);         \
    c10 = __builtin_amdgcn_mfma_f32_16x16x32_bf16(A0, B1, c10, 0, 0, 0);         \
    c11 = __builtin_amdgcn_mfma_f32_16x16x32_bf16(A1, B1, c11, 0, 0, 0);         \
    c12 = __builtin_amdgcn_mfma_f32_16x16x32_bf16(A2, B1, c12, 0, 0, 0);         \
    c13 = __builtin_amdgcn_mfma_f32_16x16x32_bf16(A3, B1, c13, 0, 0, 0);         \
    c20 = __builtin_amdgcn_mfma_f32_16x16x32_bf16(A0, B2, c20, 0, 0, 0);         \
    c21 = __builtin_amdgcn_mfma_f32_16x16x32_bf16(A1, B2, c21, 0, 0, 0);         \
    c22 = __builtin_amdgcn_mfma_f32_16x16x32_bf16(A2, B2, c22, 0, 0, 0);         \
    c23 = __builtin_amdgcn_mfma_f32_16x16x32_bf16(A3, B2, c23, 0, 0, 0);         \
    c30 = __builtin_amdgcn_mfma_f32_16x16x32_bf16(A0, B3, c30, 0, 0, 0);         \
    c31 = __builtin_amdgcn_mfma_f32_16x16x32_bf16(A1, B3, c31, 0, 0, 0);         \
    c32 = __builtin_amdgcn_mfma_f32_16x16x32_bf16(A2, B3, c32, 0, 0, 0);         \
    c33 = __builtin_amdgcn_mfma_f32_16x16x32_bf16(A3, B3, c33, 0, 0, 0);         \
} while (0)

    // rotate-prefetch pipeline, distance 1
    bf16x8 pb0 = wp0[0], pb1 = wp1[0], pb2 = wp2[0], pb3 = wp3[0];
    #pragma unroll 2
    for (int kk = 0; kk < KT1 - 1; ++kk) {
        bf16x8 b0 = pb0, b1 = pb1, b2 = pb2, b3 = pb3;
        pb0 = wp0[(kk + 1) * 64];
        pb1 = wp1[(kk + 1) * 64];
        pb2 = wp2[(kk + 1) * 64];
        pb3 = wp3[(kk + 1) * 64];
        bf16x8 a0, a1, a2, a3;
        ALOAD1(kk, a0, a1, a2, a3);
        MFMA16(a0, a1, a2, a3, b0, b1, b2, b3);
    }
    {
        bf16x8 a0, a1, a2, a3;
        ALOAD1(KT1 - 1, a0, a1, a2, a3);
        MFMA16(a0, a1, a2, a3, pb0, pb1, pb2, pb3);
    }
#undef ALOAD1
#undef MFMA16

#define EPIM1(MT, CM) do {                                                       \
    int bl = (MT) >> 1;                                                          \
    int mloc = ((MT) & 1) * 16;                                                  \
    int bb = 2 * blk + bl;                                                       \
    _Pragma("unroll")                                                            \
    for (int hf = 0; hf < 2; ++hf) {                                             \
        int wl = mloc + 4 * g + 2 * hf;                                          \
        int tp = wl >> 1;                                                        \
        if (tp < 14) {                                                           \
            float v0 = CM[2*hf] + bia, v1 = CM[2*hf+1] + bia;                    \
            v0 = LEAKY(v0); v1 = LEAKY(v1);                                      \
            int rb = bl * 32 + wl;                                               \
            if (rs[rb] + rs[rb+1] + rs[rb+2] == 0.f) v0 = 0.f;                   \
            if (rs[rb+1] + rs[rb+2] + rs[rb+3] == 0.f) v1 = 0.f;                 \
            y[(size_t)(bb * 14 + tp) * C1 + ch] = fmaxf(v0, v1);                 \
        }                                                                        \
    }                                                                            \
} while (0)

#define EPI1(NTI, CA, CB, CC, CD) do {                                           \
    int ch = (wid + 4 * (NTI)) * 16 + trow;                                      \
    if (ch < C1) {                                                               \
        float bia = bias[ch];                                                    \
        EPIM1(0, CA); EPIM1(1, CB); EPIM1(2, CC); EPIM1(3, CD);                  \
    }                                                                            \
} while (0)

    EPI1(0, c00, c01, c02, c03);
    EPI1(1, c10, c11, c12, c13);
    EPI1(2, c20, c21, c22, c23);
    EPI1(3, c30, c31, c32, c33);
#undef EPI1
#undef EPIM1
}

// ================= conv2: 4 batches/block, wave = 5 nt x 4 batch-M-tiles ========
__global__ __launch_bounds__(256, 2) void conv2_mfma(
    const float* __restrict__ x, const unsigned short* __restrict__ Wt,
    const float* __restrict__ bias, float* __restrict__ y)
{
    const int blk = blockIdx.x;            // batches 4*blk .. 4*blk+3
    const int tid = threadIdx.x;
    __shared__ unsigned short xs[72 * 256];
    __shared__ float rs[72];
    char* xsb = reinterpret_cast<char*>(xs);

    for (int idx = tid; idx < 72 * 32; idx += 256) {
        int rg = idx >> 5, ck = idx & 31;
        int bl = rg / 18, r = rg % 18;
        ushort4 lo = {0,0,0,0}, hi = {0,0,0,0};
        if (r < 14 && ck < 25) {
            const float4* src = reinterpret_cast<const float4*>(
                x + ((size_t)(4 * blk + bl) * 14 + r) * C1 + ck * 8);
            float4 a = src[0], c = src[1];
            lo = ushort4{f2bf(a.x),f2bf(a.y),f2bf(a.z),f2bf(a.w)};
            hi = ushort4{f2bf(c.x),f2bf(c.y),f2bf(c.z),f2bf(c.w)};
        }
        int bo_ = rg * 512 + ((ck ^ (rg & 7)) << 4);
        *reinterpret_cast<ushort4*>(xsb + bo_)     = lo;
        *reinterpret_cast<ushort4*>(xsb + bo_ + 8) = hi;
    }
    __syncthreads();

    const int wid = tid >> 6, lane = tid & 63;
    const int kg = lane >> 4, trow = lane & 15, g = kg;

    for (int r = wid; r < 72; r += 4) {
        float s = 0.f;
        #pragma unroll
        for (int j = 0; j < 4; ++j) {
            int e = lane + 64 * j;
            int chunk = e >> 3, within = e & 7;
            s += bf2f(*reinterpret_cast<unsigned short*>(
                xsb + r * 512 + ((chunk ^ (r & 7)) << 4) + within * 2));
        }
        for (int off = 32; off; off >>= 1) s += __shfl_down(s, off);
        if (lane == 0) rs[r] = s;
    }
    __syncthreads();

    const bf16x8* wb = reinterpret_cast<const bf16x8*>(Wt);
    const bf16x8* wp0 = wb + (size_t)((wid     ) * KT2) * 64 + lane;
    const bf16x8* wp1 = wb + (size_t)((wid +  4) * KT2) * 64 + lane;
    const bf16x8* wp2 = wb + (size_t)((wid +  8) * KT2) * 64 + lane;
    const bf16x8* wp3 = wb + (size_t)((wid + 12) * KT2) * 64 + lane;
    const bf16x8* wp4 = wb + (size_t)((wid + 16) * KT2) * 64 + lane;

    f32x4 d00={0,0,0,0},d01={0,0,0,0},d02={0,0,0,0},d03={0,0,0,0};
    f32x4 d10={0,0,0,0},d11={0,0,0,0},d12={0,0,0,0},d13={0,0,0,0};
    f32x4 d20={0,0,0,0},d21={0,0,0,0},d22={0,0,0,0},d23={0,0,0,0};
    f32x4 d30={0,0,0,0},d31={0,0,0,0},d32={0,0,0,0},d33={0,0,0,0};
    f32x4 d40={0,0,0,0},d41={0,0,0,0},d42={0,0,0,0},d43={0,0,0,0};

    int kidx = 0;
    #pragma unroll
    for (int rowoff = 0; rowoff < 3; ++rowoff) {
        #pragma unroll
        for (int cc = 0; cc < 7; ++cc, ++kidx) {
            int chunk = cc * 4 + kg;
            int R0 = trow + rowoff;
            int R1 = R0 + 18, R2 = R0 + 36, R3 = R0 + 54;
            bf16x8 a0 = *reinterpret_cast<const bf16x8*>(xsb + R0*512 + ((chunk ^ (R0 & 7)) << 4));
            bf16x8 a1 = *reinterpret_cast<const bf16x8*>(xsb + R1*512 + ((chunk ^ (R1 & 7)) << 4));
            bf16x8 a2 = *reinterpret_cast<const bf16x8*>(xsb + R2*512 + ((chunk ^ (R2 & 7)) << 4));
            bf16x8 a3 = *reinterpret_cast<const bf16x8*>(xsb + R3*512 + ((chunk ^ (R3 & 7)) << 4));
            bf16x8 b0 = wp0[kidx * 64];
            bf16x8 b1 = wp1[kidx * 64];
            bf16x8 b2 = wp2[kidx * 64];
            bf16x8 b3 = wp3[kidx * 64];
            bf16x8 b4 = wp4[kidx * 64];
            d00 = __builtin_amdgcn_mfma_f32_16x16x32_bf16(a0, b0, d00, 0, 0, 0);
            d01 = __builtin_amdgcn_mfma_f32_16x16x32_bf16(a1, b0, d01, 0, 0, 0);
            d02 = __builtin_amdgcn_mfma_f32_16x16x32_bf16(a2, b0, d02, 0, 0, 0);
            d03 = __builtin_amdgcn_mfma_f32_16x16x32_bf16(a3, b0, d03, 0, 0, 0);
            d10 = __builtin_amdgcn_mfma_f32_16x16x32_bf16(a0, b1, d10, 0, 0, 0);
            d11 = __builtin_amdgcn_mfma_f32_16x16x32_bf16(a1, b1, d11, 0, 0, 0);
            d12 = __builtin_amdgcn_mfma_f32_16x16x32_bf16(a2, b1, d12, 0, 0, 0);
            d13 = __builtin_amdgcn_mfma_f32_16x16x32_bf16(a3, b1, d13, 0, 0, 0);
            d20 = __builtin_amdgcn_mfma_f32_16x16x32_bf16(a0, b2, d20, 0, 0, 0);
            d21 = __builtin_amdgcn_mfma_f32_16x16x32_bf16(a1, b2, d21, 0, 0, 0);
            d22 = __builtin_amdgcn_mfma_f32_16x16x32_bf16(a2, b2, d22, 0, 0, 0);
            d23 = __builtin_amdgcn_mfma_f32_16x16x32_bf16(a3, b2, d23, 0, 0, 0);
            d30 = __builtin_amdgcn_mfma_f32_16x16x32_bf16(a0, b3, d30, 0, 0, 0);
            d31 = __builtin_amdgcn_mfma_f32_16x16x32_bf16(a1, b3, d31, 0, 0, 0);
            d32 = __builtin_amdgcn_mfma_f32_16x16x32_bf16(a2, b3, d32, 0, 0, 0);
            d33 = __builtin_amdgcn_mfma_f32_16x16x32_bf16(a3, b3, d33, 0, 0, 0);
            d40 = __builtin_amdgcn_mfma_f32_16x16x32_bf16(a0, b4, d40, 0, 0, 0);
            d41 = __builtin_amdgcn_mfma_f32_16x16x32_bf16(a1, b4, d41, 0, 0, 0);
            d42 = __builtin_amdgcn_mfma_f32_16x16x32_bf16(a2, b4, d42, 0, 0, 0);
            d43 = __builtin_amdgcn_mfma_f32_16x16x32_bf16(a3, b4, d43, 0, 0, 0);
        }
    }

#define EPI2B(BL, DM) do {                                                       \
    _Pragma("unroll")                                                            \
    for (int hf = 0; hf < 2; ++hf) {                                             \
        int t0 = 4 * g + 2 * hf;                                                 \
        if (t0 < 12) {                                                           \
            float v0 = LEAKY(DM[2*hf]   + bia);                                  \
            float v1 = LEAKY(DM[2*hf+1] + bia);                                  \
            int rb = (BL) * 18 + t0;                                             \
            if (rs[rb] + rs[rb+1] + rs[rb+2] == 0.f) v0 = 0.f;                   \
            if (rs[rb+1] + rs[rb+2] + rs[rb+3] == 0.f) v1 = 0.f;                 \
            y[((size_t)(4 * blk + (BL)) * 6 + (t0 >> 1)) * C2 + ch] = fmaxf(v0, v1); \
        }                                                                        \
    }                                                                            \
} while (0)

#define EPI2(NTI, DA, DB, DC, DD) do {                                           \
    int ch = (wid + 4 * (NTI)) * 16 + trow;                                      \
    if (ch < C2) {                                                               \
        float bia = bias[ch];                                                    \
        EPI2B(0, DA); EPI2B(1, DB); EPI2B(2, DC); EPI2B(3, DD);                  \
    }                                                                            \
} while (0)

    EPI2(0, d00, d01, d02, d03);
    EPI2(1, d10, d11, d12, d13);
    EPI2(2, d20, d21, d22, d23);
    EPI2(3, d30, d31, d32, d33);
    EPI2(4, d40, d41, d42, d43);
#undef EPI2
#undef EPI2B
}

// ================= conv3: 8 batches/block, wave = 5 nt x 2 group-tiles ==========
__global__ __launch_bounds__(256, 2) void conv3_mfma(
    const float* __restrict__ x, const unsigned short* __restrict__ Wt,
    const float* __restrict__ bias, float* __restrict__ y)
{
    const int b0  = blockIdx.x * 8;
    const int tid = threadIdx.x;
    __shared__ unsigned short xs[48 * 320];
    __shared__ float rs[48];
    char* xsb = reinterpret_cast<char*>(xs);

    for (int idx = tid; idx < 48 * 40; idx += 256) {
        int rg = idx / 40, ck = idx % 40;
        int c0 = ck * 8;
        ushort4 lo = {0,0,0,0}, hi = {0,0,0,0};
        const float* row = x + ((size_t)b0 * 6 + rg) * C2;
        if (c0 + 8 <= C2) {
            const float4* src = reinterpret_cast<const float4*>(row + c0);
            float4 a = src[0], c = src[1];
            lo = ushort4{f2bf(a.x),f2bf(a.y),f2bf(a.z),f2bf(a.w)};
            hi = ushort4{f2bf(c.x),f2bf(c.y),f2bf(c.z),f2bf(c.w)};
        } else if (c0 < C2) {
            unsigned short v[8];
            #pragma unroll
            for (int j = 0; j < 8; ++j)
                v[j] = (c0 + j < C2) ? f2bf(row[c0 + j]) : (unsigned short)0;
            lo = ushort4{v[0],v[1],v[2],v[3]};
            hi = ushort4{v[4],v[5],v[6],v[7]};
        }
        int bo_ = rg * 640 + ((ck ^ (rg & 7)) << 4);
        *reinterpret_cast<ushort4*>(xsb + bo_)     = lo;
        *reinterpret_cast<ushort4*>(xsb + bo_ + 8) = hi;
    }
    __syncthreads();

    const int wid = tid >> 6, lane = tid & 63;
    const int kg = lane >> 4, trow = lane & 15, g = kg;

    for (int r = wid; r < 48; r += 4) {
        float s = 0.f;
        #pragma unroll
        for (int j = 0; j < 5; ++j) {
            int e = lane + 64 * j;
            int chunk = e >> 3, within = e & 7;
            s += bf2f(*reinterpret_cast<unsigned short*>(
                xsb + r * 640 + ((chunk ^ (r & 7)) << 4) + within * 2));
        }
        for (int off = 32; off; off >>= 1) s += __shfl_down(s, off);
        if (lane == 0) rs[r] = s;
    }
    __syncthreads();

    const int rbase = 6 * (trow >> 2) + (trow & 3);

    const bf16x8* wb = reinterpret_cast<const bf16x8*>(Wt);
    const bf16x8* wp0 = wb + (size_t)((wid     ) * KT3) * 64 + lane;
    const bf16x8* wp1 = wb + (size_t)((wid +  4) * KT3) * 64 + lane;
    const bf16x8* wp2 = wb + (size_t)((wid +  8) * KT3) * 64 + lane;
    const bf16x8* wp3 = wb + (size_t)((wid + 12) * KT3) * 64 + lane;
    const bf16x8* wp4 = wb + (size_t)((wid + 16) * KT3) * 64 + lane;

    f32x4 e00={0,0,0,0},e01={0,0,0,0};
    f32x4 e10={0,0,0,0},e11={0,0,0,0};
    f32x4 e20={0,0,0,0},e21={0,0,0,0};
    f32x4 e30={0,0,0,0},e31={0,0,0,0};
    f32x4 e40={0,0,0,0},e41={0,0,0,0};

    int kidx = 0;
    #pragma unroll
    for (int rowoff = 0; rowoff < 3; ++rowoff) {
        #pragma unroll
        for (int cc = 0; cc < 10; ++cc, ++kidx) {
            int chunk = cc * 4 + kg;
            int R0 = rbase + rowoff;
            int R1 = R0 + 24;
            bf16x8 a0 = *reinterpret_cast<const bf16x8*>(xsb + R0*640 + ((chunk ^ (R0 & 7)) << 4));
            bf16x8 a1 = *reinterpret_cast<const bf16x8*>(xsb + R1*640 + ((chunk ^ (R1 & 7)) << 4));
            bf16x8 b0 = wp0[kidx * 64];
            bf16x8 b1 = wp1[kidx * 64];
            bf16x8 b2 = wp2[kidx * 64];
            bf16x8 b3 = wp3[kidx * 64];
            bf16x8 b4 = wp4[kidx * 64];
            e00 = __builtin_amdgcn_mfma_f32_16x16x32_bf16(a0, b0, e00, 0, 0, 0);
            e01 = __builtin_amdgcn_mfma_f32_16x16x32_bf16(a1, b0, e01, 0, 0, 0);
            e10 = __builtin_amdgcn_mfma_f32_16x16x32_bf16(a0, b1, e10, 0, 0, 0);
            e11 = __builtin_amdgcn_mfma_f32_16x16x32_bf16(a1, b1, e11, 0, 0, 0);
            e20 = __builtin_amdgcn_mfma_f32_16x16x32_bf16(a0, b2, e20, 0, 0, 0);
            e21 = __builtin_amdgcn_mfma_f32_16x16x32_bf16(a1, b2, e21, 0, 0, 0);
            e30 = __builtin_amdgcn_mfma_f32_16x16x32_bf16(a0, b3, e30, 0, 0, 0);
            e31 = __builtin_amdgcn_mfma_f32_16x16x32_bf16(a1, b3, e31, 0, 0, 0);
            e40 = __builtin_amdgcn_mfma_f32_16x16x32_bf16(a0, b4, e40, 0, 0, 0);
            e41 = __builtin_amdgcn_mfma_f32_16x16x32_bf16(a1, b4, e41, 0, 0, 0);
        }
    }

#define EPI3G(GR, EM) do {                                                       \
    _Pragma("unroll")                                                            \
    for (int tp = 0; tp < 2; ++tp) {                                             \
        int rb = (GR) * 24 + g * 6 + 2 * tp;                                     \
        float v0 = LEAKY(EM[2*tp]   + bia);                                      \
        float v1 = LEAKY(EM[2*tp+1] + bia);                                      \
        if (rs[rb] + rs[rb+1] + rs[rb+2] == 0.f) v0 = 0.f;                       \
        if (rs[rb+1] + rs[rb+2] + rs[rb+3] == 0.f) v1 = 0.f;                     \
        y[((size_t)(b0 + (GR) * 4 + g) * 2 + tp) * C3 + ch] = fmaxf(v0, v1);     \
    }                                                                            \
} while (0)

#define EPI3(NTI, EA, EB) do {                                                   \
    int ch = (wid + 4 * (NTI)) * 16 + trow;                                      \
    if (ch < C3) {                                                               \
        float bia = bias[ch];                                                    \
        EPI3G(0, EA); EPI3G(1, EB);                                              \
    }                                                                            \
} while (0)

    EPI3(0, e00, e01);
    EPI3(1, e10, e11);
    EPI3(2, e20, e21);
    EPI3(3, e30, e31);
    EPI3(4, e40, e41);
#undef EPI3
#undef EPI3G
}

// ================= feats concat: [y3 | image] -> bf16 [B][2656] =================
__global__ __launch_bounds__(256) void concat_feats(
    const float* __restrict__ y3, const float* __restrict__ img,
    unsigned short* __restrict__ feats)
{
    const int b = blockIdx.x;
    for (int ck = threadIdx.x; ck < FK / 8; ck += 256) {
        int c0 = ck * 8;
        ushort4 lo = {0,0,0,0}, hi = {0,0,0,0};
        const float4* src = nullptr;
        if (c0 + 8 <= 600)       src = reinterpret_cast<const float4*>(y3 + (size_t)b*600 + c0);
        else if (c0 + 8 <= 2648) src = reinterpret_cast<const float4*>(img + (size_t)b*IMG + (c0-600));
        if (src) {
            float4 a = src[0], c = src[1];
            lo = ushort4{f2bf(a.x),f2bf(a.y),f2bf(a.z),f2bf(a.w)};
            hi = ushort4{f2bf(c.x),f2bf(c.y),f2bf(c.z),f2bf(c.w)};
        }
        ushort4* dst = reinterpret_cast<ushort4*>(feats + (size_t)b * FK + c0);
        dst[0] = lo; dst[1] = hi;
    }
}

// ================= final GEMM: 448 blocks x 1 wave, wave = (mt, 4 nts), pipelined
__global__ __launch_bounds__(64) void final_mfma(
    const unsigned short* __restrict__ feats, const unsigned short* __restrict__ Wmt,
    const float* __restrict__ bm, float* __restrict__ h)
{
    const int lane = threadIdx.x;
    const int bid  = blockIdx.x;
    const int mt = bid / 7, q = bid % 7;            // 64 mt x 7 q-groups
    const int kg = lane >> 4, trow = lane & 15, g = kg;
    const int m0 = mt * 16;

    const bf16x8* ap = reinterpret_cast<const bf16x8*>(feats)
                       + (size_t)(m0 + trow) * (FK / 8) + kg;
    const bf16x8* wb = reinterpret_cast<const bf16x8*>(Wmt);
    const bf16x8* wp0 = wb + (size_t)((q     ) * KTM) * 64 + lane;
    const bf16x8* wp1 = wb + (size_t)((q +  7) * KTM) * 64 + lane;
    const bf16x8* wp2 = wb + (size_t)((q + 14) * KTM) * 64 + lane;
    const bf16x8* wp3 = wb + (size_t)((q + 21) * KTM) * 64 + lane;

    f32x4 c0 = {0,0,0,0}, c1 = {0,0,0,0}, c2 = {0,0,0,0}, c3 = {0,0,0,0};

    bf16x8 pa  = ap[0];
    bf16x8 pb0 = wp0[0], pb1 = wp1[0], pb2 = wp2[0], pb3 = wp3[0];
    for (int kk = 0; kk < KTM - 1; ++kk) {
        bf16x8 a = pa, b0 = pb0, b1 = pb1, b2 = pb2, b3 = pb3;
        pa  = ap[(kk + 1) * 4];
        pb0 = wp0[(kk + 1) * 64];
        pb1 = wp1[(kk + 1) * 64];
        pb2 = wp2[(kk + 1) * 64];
        pb3 = wp3[(kk + 1) * 64];
        c0 = __builtin_amdgcn_mfma_f32_16x16x32_bf16(a, b0, c0, 0, 0, 0);
        c1 = __builtin_amdgcn_mfma_f32_16x16x32_bf16(a, b1, c1, 0, 0, 0);
        c2 = __builtin_amdgcn_mfma_f32_16x16x32_bf16(a, b2, c2, 0, 0, 0);
        c3 = __builtin_amdgcn_mfma_f32_16x16x32_bf16(a, b3, c3, 0, 0, 0);
    }
    c0 = __builtin_amdgcn_mfma_f32_16x16x32_bf16(pa, pb0, c0, 0, 0, 0);
    c1 = __builtin_amdgcn_mfma_f32_16x16x32_bf16(pa, pb1, c1, 0, 0, 0);
    c2 = __builtin_amdgcn_mfma_f32_16x16x32_bf16(pa, pb2, c2, 0, 0, 0);
    c3 = __builtin_amdgcn_mfma_f32_16x16x32_bf16(pa, pb3, c3, 0, 0, 0);

#define EPIM(NT, CM) do {                                                        \
    int ch = (NT) * 16 + trow;                                                   \
    if (ch < LIN2) {                                                             \
        float bia = bm[ch];                                                      \
        _Pragma("unroll")                                                        \
        for (int reg = 0; reg < 4; ++reg) {                                      \
            float v = LEAKY(CM[reg] + bia);                                      \
            h[(size_t)(m0 + 4 * g + reg) * LIN2 + ch] = v;                       \
        }                                                                        \
    }                                                                            \
} while (0)

    EPIM(q,      c0);
    EPIM(q + 7,  c1);
    EPIM(q + 14, c2);
    EPIM(q + 21, c3);
#undef EPIM
}

// ================= out[b] = h[b] . Wo + bo ======================================
__global__ __launch_bounds__(256) void final_reduce(
    const float* __restrict__ h, const float* __restrict__ Wo,
    const float* __restrict__ bo, float* __restrict__ out)
{
    const int tid = threadIdx.x;
    const int wid = tid >> 6, lane = tid & 63;
    const int b = blockIdx.x * 4 + wid;
    float s = 0.f;
    #pragma unroll
    for (int j = 0; j < 7; ++j) {
        int o = lane + 64 * j;
        if (o < LIN2) s += h[(size_t)b * LIN2 + o] * Wo[o];
    }
    for (int off = 32; off; off >>= 1) s += __shfl_down(s, off);
    if (lane == 0) out[b] = s + bo[0];
}

extern "C" void kernel_launch(void* const* d_in, const int* in_sizes, int n_in,
                              void* d_out, int out_size, void* d_ws, size_t ws_size,
                              hipStream_t stream) {
    const float* image = (const float*)d_in[0];
    const int*   sent  = (const int*)  d_in[1];
    const float* emb   = (const float*)d_in[2];
    const float* W1    = (const float*)d_in[3];
    const float* b1    = (const float*)d_in[4];
    const float* W2    = (const float*)d_in[5];
    const float* b2    = (const float*)d_in[6];
    const float* W3    = (const float*)d_in[7];
    const float* b3    = (const float*)d_in[8];
    const float* Wm    = (const float*)d_in[9];
    const float* bm    = (const float*)d_in[10];
    const float* Wo    = (const float*)d_in[11];
    const float* bo    = (const float*)d_in[12];
    float* out = (float*)d_out;

    float* y1 = (float*)d_ws;                          // 2,867,200 f
    float* y2 = y1 + 2867200;                          // 1,843,200 f
    float* y3 = y2 + 1843200;                          //   614,400 f
    unsigned short* W1t = (unsigned short*)(y3 + 614400);   // T1*512
    unsigned short* W2t = W1t + (size_t)T1 * 512;            // T2*512
    unsigned short* W3t = W2t + (size_t)T2 * 512;            // T3*512
    unsigned short* Wmt = W3t + (size_t)T3 * 512;            // TM*512
    unsigned short* feats = (unsigned short*)y1;             // reuse y1 region
    float* h = y2;                                           // reuse y2 region

    convert_all<<<(TTOT * 64 + 255) / 256, 256, 0, stream>>>(
        W1, W2, W3, Wm, W1t, W2t, W3t, Wmt);

    conv1_mfma<<<B_ / 2, 256, 0, stream>>>(sent, emb, W1t, b1, y1);
    conv2_mfma<<<B_ / 4, 256, 0, stream>>>(y1, W2t, b2, y2);
    conv3_mfma<<<B_ / 8, 256, 0, stream>>>(y2, W3t, b3, y3);
    concat_feats<<<B_, 256, 0, stream>>>(y3, image, feats);
    final_mfma<<<64 * 7, 64, 0, stream>>>(feats, Wmt, bm, h);
    final_reduce<<<B_ / 4, 256, 0, stream>>>(h, Wo, bo, out);
}

// Round 7
// 129.597 us; speedup vs baseline: 1.2419x; 1.2419x over previous
//
#include <hip/hip_runtime.h>
#include <hip/hip_bf16.h>

#define LEAKY(v) ((v) > 0.0f ? (v) : 0.01f * (v))

constexpr int B_   = 1024;
constexpr int PAD  = 30;
constexpr int E    = 512;
constexpr int IMG  = 2048;
constexpr int C1   = 200;
constexpr int C2   = 300;
constexpr int C3   = 300;
constexpr int LIN2 = 400;

constexpr int NT1P = 16, KT1 = 48;   // conv1: 256-pad x 1536
constexpr int NT2P = 20, KT2 = 21;   // conv2: 320-pad x (3x7 steps in 256-pad rows)
constexpr int NT3P = 20, KT3 = 30;   // conv3: 320-pad x (3x10 steps in 320-pad rows)
constexpr int NTMP = 28, KTM = 83;   // final: 448-pad x 2656
constexpr int FK  = 2656;            // feats K padded (2648 -> 2656)

constexpr int T1 = NT1P * KT1;       // 768
constexpr int T2 = NT2P * KT2;       // 420
constexpr int T3 = NT3P * KT3;       // 600
constexpr int TM = NTMP * KTM;       // 2324
constexpr int TTOT = T1 + T2 + T3 + TM;  // 4112

typedef __attribute__((ext_vector_type(8))) short bf16x8;
typedef __attribute__((ext_vector_type(4))) float f32x4;

__device__ inline unsigned short f2bf(float f) {
    __hip_bfloat16 h = __float2bfloat16(f);
    return *reinterpret_cast<unsigned short*>(&h);
}
__device__ inline float bf2f(unsigned short u) {
    unsigned int b = ((unsigned int)u) << 16;
    return __uint_as_float(b);
}

// ================= fused weight converter: fp32 -> bf16 fragments [nt][kk][lane][8]
__global__ __launch_bounds__(256) void convert_all(
    const float* __restrict__ W1, const float* __restrict__ W2,
    const float* __restrict__ W3, const float* __restrict__ Wm,
    unsigned short* __restrict__ W1t, unsigned short* __restrict__ W2t,
    unsigned short* __restrict__ W3t, unsigned short* __restrict__ Wmt)
{
    int idx = blockIdx.x * 256 + threadIdx.x;
    if (idx >= TTOT * 64) return;
    int lane = idx & 63, t = idx >> 6;
    unsigned short v[8];

    if (t < T1) {
        int kk = t % KT1, nt = t / KT1;
        int ch = nt * 16 + (lane & 15);
        int k0 = kk * 32 + (lane >> 4) * 8;
        #pragma unroll
        for (int j = 0; j < 8; ++j)
            v[j] = (ch < C1) ? f2bf(W1[(size_t)ch * (3*E) + k0 + j]) : (unsigned short)0;
        ushort4* dst = reinterpret_cast<ushort4*>(W1t) + (size_t)t * 128 + lane * 2;
        dst[0] = ushort4{v[0],v[1],v[2],v[3]};
        dst[1] = ushort4{v[4],v[5],v[6],v[7]};
    } else if (t < T1 + T2) {
        int tt = t - T1;
        int kk = tt % KT2, nt = tt / KT2;
        int ch = nt * 16 + (lane & 15);
        int rowoff = kk / 7;
        int cbase  = (kk % 7) * 32 + (lane >> 4) * 8;
        #pragma unroll
        for (int j = 0; j < 8; ++j) {
            int c = cbase + j;
            v[j] = (ch < C2 && c < C1) ? f2bf(W2[(size_t)ch * (3*C1) + rowoff * C1 + c])
                                       : (unsigned short)0;
        }
        ushort4* dst = reinterpret_cast<ushort4*>(W2t) + (size_t)tt * 128 + lane * 2;
        dst[0] = ushort4{v[0],v[1],v[2],v[3]};
        dst[1] = ushort4{v[4],v[5],v[6],v[7]};
    } else if (t < T1 + T2 + T3) {
        int tt = t - T1 - T2;
        int kk = tt % KT3, nt = tt / KT3;
        int ch = nt * 16 + (lane & 15);
        int rowoff = kk / 10;
        int cbase  = (kk % 10) * 32 + (lane >> 4) * 8;
        #pragma unroll
        for (int j = 0; j < 8; ++j) {
            int c = cbase + j;
            v[j] = (ch < C3 && c < C2) ? f2bf(W3[(size_t)ch * (3*C2) + rowoff * C2 + c])
                                       : (unsigned short)0;
        }
        ushort4* dst = reinterpret_cast<ushort4*>(W3t) + (size_t)tt * 128 + lane * 2;
        dst[0] = ushort4{v[0],v[1],v[2],v[3]};
        dst[1] = ushort4{v[4],v[5],v[6],v[7]};
    } else {
        int tt = t - T1 - T2 - T3;
        int kk = tt % KTM, nt = tt / KTM;
        int ch = nt * 16 + (lane & 15);
        int kbase = kk * 32 + (lane >> 4) * 8;
        #pragma unroll
        for (int j = 0; j < 8; ++j) {
            int k = kbase + j;
            v[j] = (ch < LIN2 && k < 2648) ? f2bf(Wm[(size_t)ch * 2648 + k])
                                           : (unsigned short)0;
        }
        ushort4* dst = reinterpret_cast<ushort4*>(Wmt) + (size_t)tt * 128 + lane * 2;
        dst[0] = ushort4{v[0],v[1],v[2],v[3]};
        dst[1] = ushort4{v[4],v[5],v[6],v[7]};
    }
}

// ================= conv1: 2 batches/block, 512 thr (8 waves), wave = 2 nt x 4 M ==
// LDS A: 66 rows x 512 bf16 swizzled. B-streams prefetched distance 2.
// launch_bounds(512,4): 4 waves/SIMD (2 blocks/CU), VGPR capped at 128.
__global__ __launch_bounds__(512, 4) void conv1_mfma(
    const int* __restrict__ sent, const float* __restrict__ emb,
    const unsigned short* __restrict__ W1t, const float* __restrict__ bias,
    float* __restrict__ y)
{
    const int blk = blockIdx.x;            // batches 2*blk, 2*blk+1
    const int tid = threadIdx.x;
    __shared__ unsigned short xs[66 * 512];
    __shared__ float rs[64];
    char* xsb = reinterpret_cast<char*>(xs);

    for (int idx = tid; idx < 60 * 128; idx += 512) {
        int rg = idx >> 7, c4 = idx & 127;
        int bl = rg / 30, r = rg % 30;
        int R = bl * 32 + r;
        int row = sent[(2 * blk + bl) * PAD + r];
        float4 v = reinterpret_cast<const float4*>(emb + (size_t)row * E)[c4];
        ushort4 h = {f2bf(v.x), f2bf(v.y), f2bf(v.z), f2bf(v.w)};
        int chunk = c4 >> 1, half = c4 & 1;
        *reinterpret_cast<ushort4*>(
            xsb + R * 1024 + ((chunk ^ (R & 7)) << 4) + half * 8) = h;
    }
    for (int idx = tid; idx < 6 * 128; idx += 512) {
        int zi = idx >> 7, c4 = idx & 127;
        int R = (zi < 2) ? (30 + zi) : (60 + zi);
        int chunk = c4 >> 1, half = c4 & 1;
        *reinterpret_cast<ushort4*>(
            xsb + R * 1024 + ((chunk ^ (R & 7)) << 4) + half * 8) = ushort4{0,0,0,0};
    }
    __syncthreads();

    const int wid = tid >> 6, lane = tid & 63;    // wid 0..7

    for (int r = wid; r < 64; r += 8) {
        float s = 0.f;
        #pragma unroll
        for (int j = 0; j < 8; ++j) {
            int e = lane + 64 * j;
            int chunk = e >> 3, within = e & 7;
            s += bf2f(*reinterpret_cast<unsigned short*>(
                xsb + r * 1024 + ((chunk ^ (r & 7)) << 4) + within * 2));
        }
        for (int off = 32; off; off >>= 1) s += __shfl_down(s, off);
        if (lane == 0) rs[r] = s;
    }
    __syncthreads();

    const int kg = lane >> 4, trow = lane & 15, g = kg;

    const bf16x8* wb = reinterpret_cast<const bf16x8*>(W1t);
    const bf16x8* wp0 = wb + (size_t)((wid    ) * KT1) * 64 + lane;
    const bf16x8* wp1 = wb + (size_t)((wid + 8) * KT1) * 64 + lane;

    // c<nt><mt>
    f32x4 c00={0,0,0,0},c01={0,0,0,0},c02={0,0,0,0},c03={0,0,0,0};
    f32x4 c10={0,0,0,0},c11={0,0,0,0},c12={0,0,0,0},c13={0,0,0,0};

#define ALOAD1(KK, A0, A1, A2, A3) do {                                          \
    int chunk_  = ((KK) & 15) * 4 + kg;                                          \
    int rowoff_ = (KK) >> 4;                                                     \
    int R0_ = trow + rowoff_;                                                    \
    int R1_ = R0_ + 16, R2_ = R0_ + 32, R3_ = R0_ + 48;                          \
    A0 = *reinterpret_cast<const bf16x8*>(xsb + R0_*1024 + ((chunk_ ^ (R0_ & 7)) << 4)); \
    A1 = *reinterpret_cast<const bf16x8*>(xsb + R1_*1024 + ((chunk_ ^ (R1_ & 7)) << 4)); \
    A2 = *reinterpret_cast<const bf16x8*>(xsb + R2_*1024 + ((chunk_ ^ (R2_ & 7)) << 4)); \
    A3 = *reinterpret_cast<const bf16x8*>(xsb + R3_*1024 + ((chunk_ ^ (R3_ & 7)) << 4)); \
} while (0)

#define MFMA8(A0, A1, A2, A3, B0, B1) do {                                       \
    c00 = __builtin_amdgcn_mfma_f32_16x16x32_bf16(A0, B0, c00, 0, 0, 0);         \
    c01 = __builtin_amdgcn_mfma_f32_16x16x32_bf16(A1, B0, c01, 0, 0, 0);         \
    c02 = __builtin_amdgcn_mfma_f32_16x16x32_bf16(A2, B0, c02, 0, 0, 0);         \
    c03 = __builtin_amdgcn_mfma_f32_16x16x32_bf16(A3, B0, c03, 0, 0, 0);         \
    c10 = __builtin_amdgcn_mfma_f32_16x16x32_bf16(A0, B1, c10, 0, 0, 0);         \
    c11 = __builtin_amdgcn_mfma_f32_16x16x32_bf16(A1, B1, c11, 0, 0, 0);         \
    c12 = __builtin_amdgcn_mfma_f32_16x16x32_bf16(A2, B1, c12, 0, 0, 0);         \
    c13 = __builtin_amdgcn_mfma_f32_16x16x32_bf16(A3, B1, c13, 0, 0, 0);         \
} while (0)

    // rotate-prefetch pipeline, distance 2
    bf16x8 b0a = wp0[0],  b1a = wp1[0];
    bf16x8 b0b = wp0[64], b1b = wp1[64];
    #pragma unroll 2
    for (int kk = 0; kk < KT1 - 2; ++kk) {
        bf16x8 b0 = b0a, b1 = b1a;
        b0a = b0b; b1a = b1b;
        b0b = wp0[(kk + 2) * 64];
        b1b = wp1[(kk + 2) * 64];
        bf16x8 a0, a1, a2, a3;
        ALOAD1(kk, a0, a1, a2, a3);
        MFMA8(a0, a1, a2, a3, b0, b1);
    }
    {   // kk = KT1-2
        bf16x8 b0 = b0a, b1 = b1a;
        b0a = b0b; b1a = b1b;
        bf16x8 a0, a1, a2, a3;
        ALOAD1(KT1 - 2, a0, a1, a2, a3);
        MFMA8(a0, a1, a2, a3, b0, b1);
    }
    {   // kk = KT1-1
        bf16x8 a0, a1, a2, a3;
        ALOAD1(KT1 - 1, a0, a1, a2, a3);
        MFMA8(a0, a1, a2, a3, b0a, b1a);
    }
#undef ALOAD1
#undef MFMA8

#define EPIM1(MT, CM) do {                                                       \
    int bl = (MT) >> 1;                                                          \
    int mloc = ((MT) & 1) * 16;                                                  \
    int bb = 2 * blk + bl;                                                       \
    _Pragma("unroll")                                                            \
    for (int hf = 0; hf < 2; ++hf) {                                             \
        int wl = mloc + 4 * g + 2 * hf;                                          \
        int tp = wl >> 1;                                                        \
        if (tp < 14) {                                                           \
            float v0 = CM[2*hf] + bia, v1 = CM[2*hf+1] + bia;                    \
            v0 = LEAKY(v0); v1 = LEAKY(v1);                                      \
            int rb = bl * 32 + wl;                                               \
            if (rs[rb] + rs[rb+1] + rs[rb+2] == 0.f) v0 = 0.f;                   \
            if (rs[rb+1] + rs[rb+2] + rs[rb+3] == 0.f) v1 = 0.f;                 \
            y[(size_t)(bb * 14 + tp) * C1 + ch] = fmaxf(v0, v1);                 \
        }                                                                        \
    }                                                                            \
} while (0)

#define EPI1(NTI, CA, CB, CC, CD) do {                                           \
    int ch = (wid + 8 * (NTI)) * 16 + trow;                                      \
    if (ch < C1) {                                                               \
        float bia = bias[ch];                                                    \
        EPIM1(0, CA); EPIM1(1, CB); EPIM1(2, CC); EPIM1(3, CD);                  \
    }                                                                            \
} while (0)

    EPI1(0, c00, c01, c02, c03);
    EPI1(1, c10, c11, c12, c13);
#undef EPI1
#undef EPIM1
}

// ================= conv2: 4 batches/block, wave = 5 nt x 4 batch-M-tiles ========
__global__ __launch_bounds__(256, 2) void conv2_mfma(
    const float* __restrict__ x, const unsigned short* __restrict__ Wt,
    const float* __restrict__ bias, float* __restrict__ y)
{
    const int blk = blockIdx.x;            // batches 4*blk .. 4*blk+3
    const int tid = threadIdx.x;
    __shared__ unsigned short xs[72 * 256];
    __shared__ float rs[72];
    char* xsb = reinterpret_cast<char*>(xs);

    for (int idx = tid; idx < 72 * 32; idx += 256) {
        int rg = idx >> 5, ck = idx & 31;
        int bl = rg / 18, r = rg % 18;
        ushort4 lo = {0,0,0,0}, hi = {0,0,0,0};
        if (r < 14 && ck < 25) {
            const float4* src = reinterpret_cast<const float4*>(
                x + ((size_t)(4 * blk + bl) * 14 + r) * C1 + ck * 8);
            float4 a = src[0], c = src[1];
            lo = ushort4{f2bf(a.x),f2bf(a.y),f2bf(a.z),f2bf(a.w)};
            hi = ushort4{f2bf(c.x),f2bf(c.y),f2bf(c.z),f2bf(c.w)};
        }
        int bo_ = rg * 512 + ((ck ^ (rg & 7)) << 4);
        *reinterpret_cast<ushort4*>(xsb + bo_)     = lo;
        *reinterpret_cast<ushort4*>(xsb + bo_ + 8) = hi;
    }
    __syncthreads();

    const int wid = tid >> 6, lane = tid & 63;
    const int kg = lane >> 4, trow = lane & 15, g = kg;

    for (int r = wid; r < 72; r += 4) {
        float s = 0.f;
        #pragma unroll
        for (int j = 0; j < 4; ++j) {
            int e = lane + 64 * j;
            int chunk = e >> 3, within = e & 7;
            s += bf2f(*reinterpret_cast<unsigned short*>(
                xsb + r * 512 + ((chunk ^ (r & 7)) << 4) + within * 2));
        }
        for (int off = 32; off; off >>= 1) s += __shfl_down(s, off);
        if (lane == 0) rs[r] = s;
    }
    __syncthreads();

    const bf16x8* wb = reinterpret_cast<const bf16x8*>(Wt);
    const bf16x8* wp0 = wb + (size_t)((wid     ) * KT2) * 64 + lane;
    const bf16x8* wp1 = wb + (size_t)((wid +  4) * KT2) * 64 + lane;
    const bf16x8* wp2 = wb + (size_t)((wid +  8) * KT2) * 64 + lane;
    const bf16x8* wp3 = wb + (size_t)((wid + 12) * KT2) * 64 + lane;
    const bf16x8* wp4 = wb + (size_t)((wid + 16) * KT2) * 64 + lane;

    f32x4 d00={0,0,0,0},d01={0,0,0,0},d02={0,0,0,0},d03={0,0,0,0};
    f32x4 d10={0,0,0,0},d11={0,0,0,0},d12={0,0,0,0},d13={0,0,0,0};
    f32x4 d20={0,0,0,0},d21={0,0,0,0},d22={0,0,0,0},d23={0,0,0,0};
    f32x4 d30={0,0,0,0},d31={0,0,0,0},d32={0,0,0,0},d33={0,0,0,0};
    f32x4 d40={0,0,0,0},d41={0,0,0,0},d42={0,0,0,0},d43={0,0,0,0};

    int kidx = 0;
    #pragma unroll
    for (int rowoff = 0; rowoff < 3; ++rowoff) {
        #pragma unroll
        for (int cc = 0; cc < 7; ++cc, ++kidx) {
            int chunk = cc * 4 + kg;
            int R0 = trow + rowoff;
            int R1 = R0 + 18, R2 = R0 + 36, R3 = R0 + 54;
            bf16x8 a0 = *reinterpret_cast<const bf16x8*>(xsb + R0*512 + ((chunk ^ (R0 & 7)) << 4));
            bf16x8 a1 = *reinterpret_cast<const bf16x8*>(xsb + R1*512 + ((chunk ^ (R1 & 7)) << 4));
            bf16x8 a2 = *reinterpret_cast<const bf16x8*>(xsb + R2*512 + ((chunk ^ (R2 & 7)) << 4));
            bf16x8 a3 = *reinterpret_cast<const bf16x8*>(xsb + R3*512 + ((chunk ^ (R3 & 7)) << 4));
            bf16x8 b0 = wp0[kidx * 64];
            bf16x8 b1 = wp1[kidx * 64];
            bf16x8 b2 = wp2[kidx * 64];
            bf16x8 b3 = wp3[kidx * 64];
            bf16x8 b4 = wp4[kidx * 64];
            d00 = __builtin_amdgcn_mfma_f32_16x16x32_bf16(a0, b0, d00, 0, 0, 0);
            d01 = __builtin_amdgcn_mfma_f32_16x16x32_bf16(a1, b0, d01, 0, 0, 0);
            d02 = __builtin_amdgcn_mfma_f32_16x16x32_bf16(a2, b0, d02, 0, 0, 0);
            d03 = __builtin_amdgcn_mfma_f32_16x16x32_bf16(a3, b0, d03, 0, 0, 0);
            d10 = __builtin_amdgcn_mfma_f32_16x16x32_bf16(a0, b1, d10, 0, 0, 0);
            d11 = __builtin_amdgcn_mfma_f32_16x16x32_bf16(a1, b1, d11, 0, 0, 0);
            d12 = __builtin_amdgcn_mfma_f32_16x16x32_bf16(a2, b1, d12, 0, 0, 0);
            d13 = __builtin_amdgcn_mfma_f32_16x16x32_bf16(a3, b1, d13, 0, 0, 0);
            d20 = __builtin_amdgcn_mfma_f32_16x16x32_bf16(a0, b2, d20, 0, 0, 0);
            d21 = __builtin_amdgcn_mfma_f32_16x16x32_bf16(a1, b2, d21, 0, 0, 0);
            d22 = __builtin_amdgcn_mfma_f32_16x16x32_bf16(a2, b2, d22, 0, 0, 0);
            d23 = __builtin_amdgcn_mfma_f32_16x16x32_bf16(a3, b2, d23, 0, 0, 0);
            d30 = __builtin_amdgcn_mfma_f32_16x16x32_bf16(a0, b3, d30, 0, 0, 0);
            d31 = __builtin_amdgcn_mfma_f32_16x16x32_bf16(a1, b3, d31, 0, 0, 0);
            d32 = __builtin_amdgcn_mfma_f32_16x16x32_bf16(a2, b3, d32, 0, 0, 0);
            d33 = __builtin_amdgcn_mfma_f32_16x16x32_bf16(a3, b3, d33, 0, 0, 0);
            d40 = __builtin_amdgcn_mfma_f32_16x16x32_bf16(a0, b4, d40, 0, 0, 0);
            d41 = __builtin_amdgcn_mfma_f32_16x16x32_bf16(a1, b4, d41, 0, 0, 0);
            d42 = __builtin_amdgcn_mfma_f32_16x16x32_bf16(a2, b4, d42, 0, 0, 0);
            d43 = __builtin_amdgcn_mfma_f32_16x16x32_bf16(a3, b4, d43, 0, 0, 0);
        }
    }

#define EPI2B(BL, DM) do {                                                       \
    _Pragma("unroll")                                                            \
    for (int hf = 0; hf < 2; ++hf) {                                             \
        int t0 = 4 * g + 2 * hf;                                                 \
        if (t0 < 12) {                                                           \
            float v0 = LEAKY(DM[2*hf]   + bia);                                  \
            float v1 = LEAKY(DM[2*hf+1] + bia);                                  \
            int rb = (BL) * 18 + t0;                                             \
            if (rs[rb] + rs[rb+1] + rs[rb+2] == 0.f) v0 = 0.f;                   \
            if (rs[rb+1] + rs[rb+2] + rs[rb+3] == 0.f) v1 = 0.f;                 \
            y[((size_t)(4 * blk + (BL)) * 6 + (t0 >> 1)) * C2 + ch] = fmaxf(v0, v1); \
        }                                                                        \
    }                                                                            \
} while (0)

#define EPI2(NTI, DA, DB, DC, DD) do {                                           \
    int ch = (wid + 4 * (NTI)) * 16 + trow;                                      \
    if (ch < C2) {                                                               \
        float bia = bias[ch];                                                    \
        EPI2B(0, DA); EPI2B(1, DB); EPI2B(2, DC); EPI2B(3, DD);                  \
    }                                                                            \
} while (0)

    EPI2(0, d00, d01, d02, d03);
    EPI2(1, d10, d11, d12, d13);
    EPI2(2, d20, d21, d22, d23);
    EPI2(3, d30, d31, d32, d33);
    EPI2(4, d40, d41, d42, d43);
#undef EPI2
#undef EPI2B
}

// ================= conv3: 8 batches/block, wave = 5 nt x 2 group-tiles ==========
__global__ __launch_bounds__(256, 2) void conv3_mfma(
    const float* __restrict__ x, const unsigned short* __restrict__ Wt,
    const float* __restrict__ bias, float* __restrict__ y)
{
    const int b0  = blockIdx.x * 8;
    const int tid = threadIdx.x;
    __shared__ unsigned short xs[48 * 320];
    __shared__ float rs[48];
    char* xsb = reinterpret_cast<char*>(xs);

    for (int idx = tid; idx < 48 * 40; idx += 256) {
        int rg = idx / 40, ck = idx % 40;
        int c0 = ck * 8;
        ushort4 lo = {0,0,0,0}, hi = {0,0,0,0};
        const float* row = x + ((size_t)b0 * 6 + rg) * C2;
        if (c0 + 8 <= C2) {
            const float4* src = reinterpret_cast<const float4*>(row + c0);
            float4 a = src[0], c = src[1];
            lo = ushort4{f2bf(a.x),f2bf(a.y),f2bf(a.z),f2bf(a.w)};
            hi = ushort4{f2bf(c.x),f2bf(c.y),f2bf(c.z),f2bf(c.w)};
        } else if (c0 < C2) {
            unsigned short v[8];
            #pragma unroll
            for (int j = 0; j < 8; ++j)
                v[j] = (c0 + j < C2) ? f2bf(row[c0 + j]) : (unsigned short)0;
            lo = ushort4{v[0],v[1],v[2],v[3]};
            hi = ushort4{v[4],v[5],v[6],v[7]};
        }
        int bo_ = rg * 640 + ((ck ^ (rg & 7)) << 4);
        *reinterpret_cast<ushort4*>(xsb + bo_)     = lo;
        *reinterpret_cast<ushort4*>(xsb + bo_ + 8) = hi;
    }
    __syncthreads();

    const int wid = tid >> 6, lane = tid & 63;
    const int kg = lane >> 4, trow = lane & 15, g = kg;

    for (int r = wid; r < 48; r += 4) {
        float s = 0.f;
        #pragma unroll
        for (int j = 0; j < 5; ++j) {
            int e = lane + 64 * j;
            int chunk = e >> 3, within = e & 7;
            s += bf2f(*reinterpret_cast<unsigned short*>(
                xsb + r * 640 + ((chunk ^ (r & 7)) << 4) + within * 2));
        }
        for (int off = 32; off; off >>= 1) s += __shfl_down(s, off);
        if (lane == 0) rs[r] = s;
    }
    __syncthreads();

    const int rbase = 6 * (trow >> 2) + (trow & 3);

    const bf16x8* wb = reinterpret_cast<const bf16x8*>(Wt);
    const bf16x8* wp0 = wb + (size_t)((wid     ) * KT3) * 64 + lane;
    const bf16x8* wp1 = wb + (size_t)((wid +  4) * KT3) * 64 + lane;
    const bf16x8* wp2 = wb + (size_t)((wid +  8) * KT3) * 64 + lane;
    const bf16x8* wp3 = wb + (size_t)((wid + 12) * KT3) * 64 + lane;
    const bf16x8* wp4 = wb + (size_t)((wid + 16) * KT3) * 64 + lane;

    f32x4 e00={0,0,0,0},e01={0,0,0,0};
    f32x4 e10={0,0,0,0},e11={0,0,0,0};
    f32x4 e20={0,0,0,0},e21={0,0,0,0};
    f32x4 e30={0,0,0,0},e31={0,0,0,0};
    f32x4 e40={0,0,0,0},e41={0,0,0,0};

    int kidx = 0;
    #pragma unroll
    for (int rowoff = 0; rowoff < 3; ++rowoff) {
        #pragma unroll
        for (int cc = 0; cc < 10; ++cc, ++kidx) {
            int chunk = cc * 4 + kg;
            int R0 = rbase + rowoff;
            int R1 = R0 + 24;
            bf16x8 a0 = *reinterpret_cast<const bf16x8*>(xsb + R0*640 + ((chunk ^ (R0 & 7)) << 4));
            bf16x8 a1 = *reinterpret_cast<const bf16x8*>(xsb + R1*640 + ((chunk ^ (R1 & 7)) << 4));
            bf16x8 b0 = wp0[kidx * 64];
            bf16x8 b1 = wp1[kidx * 64];
            bf16x8 b2 = wp2[kidx * 64];
            bf16x8 b3 = wp3[kidx * 64];
            bf16x8 b4 = wp4[kidx * 64];
            e00 = __builtin_amdgcn_mfma_f32_16x16x32_bf16(a0, b0, e00, 0, 0, 0);
            e01 = __builtin_amdgcn_mfma_f32_16x16x32_bf16(a1, b0, e01, 0, 0, 0);
            e10 = __builtin_amdgcn_mfma_f32_16x16x32_bf16(a0, b1, e10, 0, 0, 0);
            e11 = __builtin_amdgcn_mfma_f32_16x16x32_bf16(a1, b1, e11, 0, 0, 0);
            e20 = __builtin_amdgcn_mfma_f32_16x16x32_bf16(a0, b2, e20, 0, 0, 0);
            e21 = __builtin_amdgcn_mfma_f32_16x16x32_bf16(a1, b2, e21, 0, 0, 0);
            e30 = __builtin_amdgcn_mfma_f32_16x16x32_bf16(a0, b3, e30, 0, 0, 0);
            e31 = __builtin_amdgcn_mfma_f32_16x16x32_bf16(a1, b3, e31, 0, 0, 0);
            e40 = __builtin_amdgcn_mfma_f32_16x16x32_bf16(a0, b4, e40, 0, 0, 0);
            e41 = __builtin_amdgcn_mfma_f32_16x16x32_bf16(a1, b4, e41, 0, 0, 0);
        }
    }

#define EPI3G(GR, EM) do {                                                       \
    _Pragma("unroll")                                                            \
    for (int tp = 0; tp < 2; ++tp) {                                             \
        int rb = (GR) * 24 + g * 6 + 2 * tp;                                     \
        float v0 = LEAKY(EM[2*tp]   + bia);                                      \
        float v1 = LEAKY(EM[2*tp+1] + bia);                                      \
        if (rs[rb] + rs[rb+1] + rs[rb+2] == 0.f) v0 = 0.f;                       \
        if (rs[rb+1] + rs[rb+2] + rs[rb+3] == 0.f) v1 = 0.f;                     \
        y[((size_t)(b0 + (GR) * 4 + g) * 2 + tp) * C3 + ch] = fmaxf(v0, v1);     \
    }                                                                            \
} while (0)

#define EPI3(NTI, EA, EB) do {                                                   \
    int ch = (wid + 4 * (NTI)) * 16 + trow;                                      \
    if (ch < C3) {                                                               \
        float bia = bias[ch];                                                    \
        EPI3G(0, EA); EPI3G(1, EB);                                              \
    }                                                                            \
} while (0)

    EPI3(0, e00, e01);
    EPI3(1, e10, e11);
    EPI3(2, e20, e21);
    EPI3(3, e30, e31);
    EPI3(4, e40, e41);
#undef EPI3
#undef EPI3G
}

// ================= feats concat: [y3 | image] -> bf16 [B][2656] =================
__global__ __launch_bounds__(256) void concat_feats(
    const float* __restrict__ y3, const float* __restrict__ img,
    unsigned short* __restrict__ feats)
{
    const int b = blockIdx.x;
    for (int ck = threadIdx.x; ck < FK / 8; ck += 256) {
        int c0 = ck * 8;
        ushort4 lo = {0,0,0,0}, hi = {0,0,0,0};
        const float4* src = nullptr;
        if (c0 + 8 <= 600)       src = reinterpret_cast<const float4*>(y3 + (size_t)b*600 + c0);
        else if (c0 + 8 <= 2648) src = reinterpret_cast<const float4*>(img + (size_t)b*IMG + (c0-600));
        if (src) {
            float4 a = src[0], c = src[1];
            lo = ushort4{f2bf(a.x),f2bf(a.y),f2bf(a.z),f2bf(a.w)};
            hi = ushort4{f2bf(c.x),f2bf(c.y),f2bf(c.z),f2bf(c.w)};
        }
        ushort4* dst = reinterpret_cast<ushort4*>(feats + (size_t)b * FK + c0);
        dst[0] = lo; dst[1] = hi;
    }
}

// ================= final GEMM: 448 blocks x 1 wave, wave = (mt, 4 nts), depth-2 =
__global__ __launch_bounds__(64) void final_mfma(
    const unsigned short* __restrict__ feats, const unsigned short* __restrict__ Wmt,
    const float* __restrict__ bm, float* __restrict__ h)
{
    const int lane = threadIdx.x;
    const int bid  = blockIdx.x;
    const int mt = bid / 7, q = bid % 7;            // 64 mt x 7 q-groups
    const int kg = lane >> 4, trow = lane & 15, g = kg;
    const int m0 = mt * 16;

    const bf16x8* ap = reinterpret_cast<const bf16x8*>(feats)
                       + (size_t)(m0 + trow) * (FK / 8) + kg;
    const bf16x8* wb = reinterpret_cast<const bf16x8*>(Wmt);
    const bf16x8* wp0 = wb + (size_t)((q     ) * KTM) * 64 + lane;
    const bf16x8* wp1 = wb + (size_t)((q +  7) * KTM) * 64 + lane;
    const bf16x8* wp2 = wb + (size_t)((q + 14) * KTM) * 64 + lane;
    const bf16x8* wp3 = wb + (size_t)((q + 21) * KTM) * 64 + lane;

    f32x4 c0 = {0,0,0,0}, c1 = {0,0,0,0}, c2 = {0,0,0,0}, c3 = {0,0,0,0};

    // distance-2 rotate prefetch on A and B
    bf16x8 aA = ap[0],      aB = ap[4];
    bf16x8 b0A = wp0[0],  b1A = wp1[0],  b2A = wp2[0],  b3A = wp3[0];
    bf16x8 b0B = wp0[64], b1B = wp1[64], b2B = wp2[64], b3B = wp3[64];
    for (int kk = 0; kk < KTM - 2; ++kk) {
        bf16x8 a = aA, b0 = b0A, b1 = b1A, b2 = b2A, b3 = b3A;
        aA = aB;  b0A = b0B; b1A = b1B; b2A = b2B; b3A = b3B;
        aB  = ap [(kk + 2) * 4];
        b0B = wp0[(kk + 2) * 64];
        b1B = wp1[(kk + 2) * 64];
        b2B = wp2[(kk + 2) * 64];
        b3B = wp3[(kk + 2) * 64];
        c0 = __builtin_amdgcn_mfma_f32_16x16x32_bf16(a, b0, c0, 0, 0, 0);
        c1 = __builtin_amdgcn_mfma_f32_16x16x32_bf16(a, b1, c1, 0, 0, 0);
        c2 = __builtin_amdgcn_mfma_f32_16x16x32_bf16(a, b2, c2, 0, 0, 0);
        c3 = __builtin_amdgcn_mfma_f32_16x16x32_bf16(a, b3, c3, 0, 0, 0);
    }
    c0 = __builtin_amdgcn_mfma_f32_16x16x32_bf16(aA, b0A, c0, 0, 0, 0);
    c1 = __builtin_amdgcn_mfma_f32_16x16x32_bf16(aA, b1A, c1, 0, 0, 0);
    c2 = __builtin_amdgcn_mfma_f32_16x16x32_bf16(aA, b2A, c2, 0, 0, 0);
    c3 = __builtin_amdgcn_mfma_f32_16x16x32_bf16(aA, b3A, c3, 0, 0, 0);
    c0 = __builtin_amdgcn_mfma_f32_16x16x32_bf16(aB, b0B, c0, 0, 0, 0);
    c1 = __builtin_amdgcn_mfma_f32_16x16x32_bf16(aB, b1B, c1, 0, 0, 0);
    c2 = __builtin_amdgcn_mfma_f32_16x16x32_bf16(aB, b2B, c2, 0, 0, 0);
    c3 = __builtin_amdgcn_mfma_f32_16x16x32_bf16(aB, b3B, c3, 0, 0, 0);

#define EPIM(NT, CM) do {                                                        \
    int ch = (NT) * 16 + trow;                                                   \
    if (ch < LIN2) {                                                             \
        float bia = bm[ch];                                                      \
        _Pragma("unroll")                                                        \
        for (int reg = 0; reg < 4; ++reg) {                                      \
            float v = LEAKY(CM[reg] + bia);                                      \
            h[(size_t)(m0 + 4 * g + reg) * LIN2 + ch] = v;                       \
        }                                                                        \
    }                                                                            \
} while (0)

    EPIM(q,      c0);
    EPIM(q + 7,  c1);
    EPIM(q + 14, c2);
    EPIM(q + 21, c3);
#undef EPIM
}

// ================= out[b] = h[b] . Wo + bo ======================================
__global__ __launch_bounds__(256) void final_reduce(
    const float* __restrict__ h, const float* __restrict__ Wo,
    const float* __restrict__ bo, float* __restrict__ out)
{
    const int tid = threadIdx.x;
    const int wid = tid >> 6, lane = tid & 63;
    const int b = blockIdx.x * 4 + wid;
    float s = 0.f;
    #pragma unroll
    for (int j = 0; j < 7; ++j) {
        int o = lane + 64 * j;
        if (o < LIN2) s += h[(size_t)b * LIN2 + o] * Wo[o];
    }
    for (int off = 32; off; off >>= 1) s += __shfl_down(s, off);
    if (lane == 0) out[b] = s + bo[0];
}

extern "C" void kernel_launch(void* const* d_in, const int* in_sizes, int n_in,
                              void* d_out, int out_size, void* d_ws, size_t ws_size,
                              hipStream_t stream) {
    const float* image = (const float*)d_in[0];
    const int*   sent  = (const int*)  d_in[1];
    const float* emb   = (const float*)d_in[2];
    const float* W1    = (const float*)d_in[3];
    const float* b1    = (const float*)d_in[4];
    const float* W2    = (const float*)d_in[5];
    const float* b2    = (const float*)d_in[6];
    const float* W3    = (const float*)d_in[7];
    const float* b3    = (const float*)d_in[8];
    const float* Wm    = (const float*)d_in[9];
    const float* bm    = (const float*)d_in[10];
    const float* Wo    = (const float*)d_in[11];
    const float* bo    = (const float*)d_in[12];
    float* out = (float*)d_out;

    float* y1 = (float*)d_ws;                          // 2,867,200 f
    float* y2 = y1 + 2867200;                          // 1,843,200 f
    float* y3 = y2 + 1843200;                          //   614,400 f
    unsigned short* W1t = (unsigned short*)(y3 + 614400);   // T1*512
    unsigned short* W2t = W1t + (size_t)T1 * 512;            // T2*512
    unsigned short* W3t = W2t + (size_t)T2 * 512;            // T3*512
    unsigned short* Wmt = W3t + (size_t)T3 * 512;            // TM*512
    unsigned short* feats = (unsigned short*)y1;             // reuse y1 region
    float* h = y2;                                           // reuse y2 region

    convert_all<<<(TTOT * 64 + 255) / 256, 256, 0, stream>>>(
        W1, W2, W3, Wm, W1t, W2t, W3t, Wmt);

    conv1_mfma<<<B_ / 2, 512, 0, stream>>>(sent, emb, W1t, b1, y1);
    conv2_mfma<<<B_ / 4, 256, 0, stream>>>(y1, W2t, b2, y2);
    conv3_mfma<<<B_ / 8, 256, 0, stream>>>(y2, W3t, b3, y3);
    concat_feats<<<B_, 256, 0, stream>>>(y3, image, feats);
    final_mfma<<<64 * 7, 64, 0, stream>>>(feats, Wmt, bm, h);
    final_reduce<<<B_ / 4, 256, 0, stream>>>(h, Wo, bo, out);
}

// Round 8
// 125.414 us; speedup vs baseline: 1.2833x; 1.0334x over previous
//
#include <hip/hip_runtime.h>
#include <hip/hip_bf16.h>

#define LEAKY(v) ((v) > 0.0f ? (v) : 0.01f * (v))

constexpr int B_   = 1024;
constexpr int PAD  = 30;
constexpr int E    = 512;
constexpr int IMG  = 2048;
constexpr int C1   = 200;
constexpr int C2   = 300;
constexpr int C3   = 300;
constexpr int LIN2 = 400;

constexpr int NT1P = 16, KT1 = 48;   // conv1: 256-pad x 1536
constexpr int NT2P = 20, KT2 = 21;   // conv2: 320-pad x (3x7 steps in 256-pad rows)
constexpr int NT3P = 20, KT3 = 30;   // conv3: 320-pad x (3x10 steps in 320-pad rows)
constexpr int NTMP = 28, KTM = 83;   // final: 448-pad x 2656
constexpr int FK  = 2656;            // feats K padded (2648 -> 2656)

constexpr int T1 = NT1P * KT1;       // 768
constexpr int T2 = NT2P * KT2;       // 420
constexpr int T3 = NT3P * KT3;       // 600
constexpr int TM = NTMP * KTM;       // 2324
constexpr int TTOT = T1 + T2 + T3 + TM;  // 4112

typedef __attribute__((ext_vector_type(8))) short bf16x8;
typedef __attribute__((ext_vector_type(4))) float f32x4;

__device__ inline unsigned short f2bf(float f) {
    __hip_bfloat16 h = __float2bfloat16(f);
    return *reinterpret_cast<unsigned short*>(&h);
}
__device__ inline float bf2f(unsigned short u) {
    unsigned int b = ((unsigned int)u) << 16;
    return __uint_as_float(b);
}

// ================= fused weight converter: fp32 -> bf16 fragments [nt][kk][lane][8]
__global__ __launch_bounds__(256) void convert_all(
    const float* __restrict__ W1, const float* __restrict__ W2,
    const float* __restrict__ W3, const float* __restrict__ Wm,
    unsigned short* __restrict__ W1t, unsigned short* __restrict__ W2t,
    unsigned short* __restrict__ W3t, unsigned short* __restrict__ Wmt)
{
    int idx = blockIdx.x * 256 + threadIdx.x;
    if (idx >= TTOT * 64) return;
    int lane = idx & 63, t = idx >> 6;
    unsigned short v[8];

    if (t < T1) {
        int kk = t % KT1, nt = t / KT1;
        int ch = nt * 16 + (lane & 15);
        int k0 = kk * 32 + (lane >> 4) * 8;
        #pragma unroll
        for (int j = 0; j < 8; ++j)
            v[j] = (ch < C1) ? f2bf(W1[(size_t)ch * (3*E) + k0 + j]) : (unsigned short)0;
        ushort4* dst = reinterpret_cast<ushort4*>(W1t) + (size_t)t * 128 + lane * 2;
        dst[0] = ushort4{v[0],v[1],v[2],v[3]};
        dst[1] = ushort4{v[4],v[5],v[6],v[7]};
    } else if (t < T1 + T2) {
        int tt = t - T1;
        int kk = tt % KT2, nt = tt / KT2;
        int ch = nt * 16 + (lane & 15);
        int rowoff = kk / 7;
        int cbase  = (kk % 7) * 32 + (lane >> 4) * 8;
        #pragma unroll
        for (int j = 0; j < 8; ++j) {
            int c = cbase + j;
            v[j] = (ch < C2 && c < C1) ? f2bf(W2[(size_t)ch * (3*C1) + rowoff * C1 + c])
                                       : (unsigned short)0;
        }
        ushort4* dst = reinterpret_cast<ushort4*>(W2t) + (size_t)tt * 128 + lane * 2;
        dst[0] = ushort4{v[0],v[1],v[2],v[3]};
        dst[1] = ushort4{v[4],v[5],v[6],v[7]};
    } else if (t < T1 + T2 + T3) {
        int tt = t - T1 - T2;
        int kk = tt % KT3, nt = tt / KT3;
        int ch = nt * 16 + (lane & 15);
        int rowoff = kk / 10;
        int cbase  = (kk % 10) * 32 + (lane >> 4) * 8;
        #pragma unroll
        for (int j = 0; j < 8; ++j) {
            int c = cbase + j;
            v[j] = (ch < C3 && c < C2) ? f2bf(W3[(size_t)ch * (3*C2) + rowoff * C2 + c])
                                       : (unsigned short)0;
        }
        ushort4* dst = reinterpret_cast<ushort4*>(W3t) + (size_t)tt * 128 + lane * 2;
        dst[0] = ushort4{v[0],v[1],v[2],v[3]};
        dst[1] = ushort4{v[4],v[5],v[6],v[7]};
    } else {
        int tt = t - T1 - T2 - T3;
        int kk = tt % KTM, nt = tt / KTM;
        int ch = nt * 16 + (lane & 15);
        int kbase = kk * 32 + (lane >> 4) * 8;
        #pragma unroll
        for (int j = 0; j < 8; ++j) {
            int k = kbase + j;
            v[j] = (ch < LIN2 && k < 2648) ? f2bf(Wm[(size_t)ch * 2648 + k])
                                           : (unsigned short)0;
        }
        ushort4* dst = reinterpret_cast<ushort4*>(Wmt) + (size_t)tt * 128 + lane * 2;
        dst[0] = ushort4{v[0],v[1],v[2],v[3]};
        dst[1] = ushort4{v[4],v[5],v[6],v[7]};
    }
}

// ================= conv1: 2 batches/block, 512 thr (8 waves), wave = 2 nt x 4 M ==
// LDS A: 66 rows x 512 bf16 swizzled. Fully unrolled K-loop, base3 XOR addressing,
// staging = 1 wave/row with b128 writes + fused fp32 rowsum.
__global__ __launch_bounds__(512, 4) void conv1_mfma(
    const int* __restrict__ sent, const float* __restrict__ emb,
    const unsigned short* __restrict__ W1t, const float* __restrict__ bias,
    float* __restrict__ y)
{
    const int blk = blockIdx.x;            // batches 2*blk, 2*blk+1
    const int tid = threadIdx.x;
    __shared__ unsigned short xs[66 * 512];
    __shared__ float rs[64];
    char* xsb = reinterpret_cast<char*>(xs);

    const int wid = tid >> 6, lane = tid & 63;    // wid 0..7

    // --- staging: wave handles whole rows (64 x 16B chunks), fused rowsum -------
    for (int r = wid; r < 60; r += 8) {
        int bl = r / 30, rr = r % 30;
        int R = bl * 32 + rr;
        int row = sent[(2 * blk + bl) * PAD + rr];
        const float4* src = reinterpret_cast<const float4*>(emb + (size_t)row * E) + lane * 2;
        float4 e0 = src[0], e1 = src[1];
        float sum = e0.x + e0.y + e0.z + e0.w + e1.x + e1.y + e1.z + e1.w;
        union { ushort4 u4[2]; bf16x8 v; } pk;
        pk.u4[0] = ushort4{f2bf(e0.x), f2bf(e0.y), f2bf(e0.z), f2bf(e0.w)};
        pk.u4[1] = ushort4{f2bf(e1.x), f2bf(e1.y), f2bf(e1.z), f2bf(e1.w)};
        int byteoff = R * 1024 + ((lane ^ (R & 7)) << 4);
        *reinterpret_cast<bf16x8*>(xsb + byteoff) = pk.v;
        for (int off = 32; off; off >>= 1) sum += __shfl_down(sum, off);
        if (lane == 0) rs[R] = sum;
    }
    // zero pad rows 30,31,62,63,64,65 (6 rows x 64 chunks = 384 tasks)
    if (tid < 384) {
        int zi = tid >> 6;                  // 0..5
        int R = (zi < 2) ? (30 + zi) : (60 + zi);
        int byteoff = R * 1024 + ((lane ^ (R & 7)) << 4);
        union { ushort4 u4[2]; bf16x8 v; } pk;
        pk.u4[0] = ushort4{0,0,0,0}; pk.u4[1] = ushort4{0,0,0,0};
        *reinterpret_cast<bf16x8*>(xsb + byteoff) = pk.v;
    }
    if (tid < 4) {
        const int pr[4] = {30, 31, 62, 63};
        rs[pr[tid]] = 0.f;
    }
    __syncthreads();

    const int kg = lane >> 4, trow = lane & 15, g = kg;

    const bf16x8* wb = reinterpret_cast<const bf16x8*>(W1t);
    const bf16x8* wp0 = wb + (size_t)((wid    ) * KT1) * 64 + lane;
    const bf16x8* wp1 = wb + (size_t)((wid + 8) * KT1) * 64 + lane;

    // c<nt><mt>
    f32x4 c00={0,0,0,0},c01={0,0,0,0},c02={0,0,0,0},c03={0,0,0,0};
    f32x4 c10={0,0,0,0},c11={0,0,0,0},c12={0,0,0,0},c13={0,0,0,0};

    #pragma unroll
    for (int rowoff = 0; rowoff < 3; ++rowoff) {
        const int R0 = trow + rowoff;
        const int R1 = R0 + 16, R2 = R0 + 32, R3 = R0 + 48;
        // addr = b3_R ^ (cc<<6)  (bit-disjoint decomposition of the swizzle)
        const int b3_0 = R0 * 1024 + (((R0 & 7) ^ kg) << 4);
        const int b3_1 = R1 * 1024 + (((R1 & 7) ^ kg) << 4);
        const int b3_2 = R2 * 1024 + (((R2 & 7) ^ kg) << 4);
        const int b3_3 = R3 * 1024 + (((R3 & 7) ^ kg) << 4);
        #pragma unroll
        for (int cc = 0; cc < 16; ++cc) {
            const int kk = rowoff * 16 + cc;
            bf16x8 a0 = *reinterpret_cast<const bf16x8*>(xsb + (b3_0 ^ (cc << 6)));
            bf16x8 a1 = *reinterpret_cast<const bf16x8*>(xsb + (b3_1 ^ (cc << 6)));
            bf16x8 a2 = *reinterpret_cast<const bf16x8*>(xsb + (b3_2 ^ (cc << 6)));
            bf16x8 a3 = *reinterpret_cast<const bf16x8*>(xsb + (b3_3 ^ (cc << 6)));
            bf16x8 b0 = wp0[kk * 64];
            bf16x8 b1 = wp1[kk * 64];
            c00 = __builtin_amdgcn_mfma_f32_16x16x32_bf16(a0, b0, c00, 0, 0, 0);
            c01 = __builtin_amdgcn_mfma_f32_16x16x32_bf16(a1, b0, c01, 0, 0, 0);
            c02 = __builtin_amdgcn_mfma_f32_16x16x32_bf16(a2, b0, c02, 0, 0, 0);
            c03 = __builtin_amdgcn_mfma_f32_16x16x32_bf16(a3, b0, c03, 0, 0, 0);
            c10 = __builtin_amdgcn_mfma_f32_16x16x32_bf16(a0, b1, c10, 0, 0, 0);
            c11 = __builtin_amdgcn_mfma_f32_16x16x32_bf16(a1, b1, c11, 0, 0, 0);
            c12 = __builtin_amdgcn_mfma_f32_16x16x32_bf16(a2, b1, c12, 0, 0, 0);
            c13 = __builtin_amdgcn_mfma_f32_16x16x32_bf16(a3, b1, c13, 0, 0, 0);
        }
    }

#define EPIM1(MT, CM) do {                                                       \
    int bl = (MT) >> 1;                                                          \
    int mloc = ((MT) & 1) * 16;                                                  \
    int bb = 2 * blk + bl;                                                       \
    _Pragma("unroll")                                                            \
    for (int hf = 0; hf < 2; ++hf) {                                             \
        int wl = mloc + 4 * g + 2 * hf;                                          \
        int tp = wl >> 1;                                                        \
        if (tp < 14) {                                                           \
            float v0 = CM[2*hf] + bia, v1 = CM[2*hf+1] + bia;                    \
            v0 = LEAKY(v0); v1 = LEAKY(v1);                                      \
            int rb = bl * 32 + wl;                                               \
            if (rs[rb] + rs[rb+1] + rs[rb+2] == 0.f) v0 = 0.f;                   \
            if (rs[rb+1] + rs[rb+2] + rs[rb+3] == 0.f) v1 = 0.f;                 \
            y[(size_t)(bb * 14 + tp) * C1 + ch] = fmaxf(v0, v1);                 \
        }                                                                        \
    }                                                                            \
} while (0)

#define EPI1(NTI, CA, CB, CC, CD) do {                                           \
    int ch = (wid + 8 * (NTI)) * 16 + trow;                                      \
    if (ch < C1) {                                                               \
        float bia = bias[ch];                                                    \
        EPIM1(0, CA); EPIM1(1, CB); EPIM1(2, CC); EPIM1(3, CD);                  \
    }                                                                            \
} while (0)

    EPI1(0, c00, c01, c02, c03);
    EPI1(1, c10, c11, c12, c13);
#undef EPI1
#undef EPIM1
}

// ================= conv2: 4 batches/block, wave = 5 nt x 4 batch-M-tiles ========
__global__ __launch_bounds__(256, 2) void conv2_mfma(
    const float* __restrict__ x, const unsigned short* __restrict__ Wt,
    const float* __restrict__ bias, float* __restrict__ y)
{
    const int blk = blockIdx.x;            // batches 4*blk .. 4*blk+3
    const int tid = threadIdx.x;
    __shared__ unsigned short xs[72 * 256];
    __shared__ float rs[72];
    char* xsb = reinterpret_cast<char*>(xs);

    for (int idx = tid; idx < 72 * 32; idx += 256) {
        int rg = idx >> 5, ck = idx & 31;
        int bl = rg / 18, r = rg % 18;
        ushort4 lo = {0,0,0,0}, hi = {0,0,0,0};
        if (r < 14 && ck < 25) {
            const float4* src = reinterpret_cast<const float4*>(
                x + ((size_t)(4 * blk + bl) * 14 + r) * C1 + ck * 8);
            float4 a = src[0], c = src[1];
            lo = ushort4{f2bf(a.x),f2bf(a.y),f2bf(a.z),f2bf(a.w)};
            hi = ushort4{f2bf(c.x),f2bf(c.y),f2bf(c.z),f2bf(c.w)};
        }
        int bo_ = rg * 512 + ((ck ^ (rg & 7)) << 4);
        *reinterpret_cast<ushort4*>(xsb + bo_)     = lo;
        *reinterpret_cast<ushort4*>(xsb + bo_ + 8) = hi;
    }
    __syncthreads();

    const int wid = tid >> 6, lane = tid & 63;
    const int kg = lane >> 4, trow = lane & 15, g = kg;

    for (int r = wid; r < 72; r += 4) {
        float s = 0.f;
        #pragma unroll
        for (int j = 0; j < 4; ++j) {
            int e = lane + 64 * j;
            int chunk = e >> 3, within = e & 7;
            s += bf2f(*reinterpret_cast<unsigned short*>(
                xsb + r * 512 + ((chunk ^ (r & 7)) << 4) + within * 2));
        }
        for (int off = 32; off; off >>= 1) s += __shfl_down(s, off);
        if (lane == 0) rs[r] = s;
    }
    __syncthreads();

    const bf16x8* wb = reinterpret_cast<const bf16x8*>(Wt);
    const bf16x8* wp0 = wb + (size_t)((wid     ) * KT2) * 64 + lane;
    const bf16x8* wp1 = wb + (size_t)((wid +  4) * KT2) * 64 + lane;
    const bf16x8* wp2 = wb + (size_t)((wid +  8) * KT2) * 64 + lane;
    const bf16x8* wp3 = wb + (size_t)((wid + 12) * KT2) * 64 + lane;
    const bf16x8* wp4 = wb + (size_t)((wid + 16) * KT2) * 64 + lane;

    f32x4 d00={0,0,0,0},d01={0,0,0,0},d02={0,0,0,0},d03={0,0,0,0};
    f32x4 d10={0,0,0,0},d11={0,0,0,0},d12={0,0,0,0},d13={0,0,0,0};
    f32x4 d20={0,0,0,0},d21={0,0,0,0},d22={0,0,0,0},d23={0,0,0,0};
    f32x4 d30={0,0,0,0},d31={0,0,0,0},d32={0,0,0,0},d33={0,0,0,0};
    f32x4 d40={0,0,0,0},d41={0,0,0,0},d42={0,0,0,0},d43={0,0,0,0};

    int kidx = 0;
    #pragma unroll
    for (int rowoff = 0; rowoff < 3; ++rowoff) {
        const int R0 = trow + rowoff;
        const int R1 = R0 + 18, R2 = R0 + 36, R3 = R0 + 54;
        const int b3_0 = R0 * 512 + (((R0 & 7) ^ kg) << 4);
        const int b3_1 = R1 * 512 + (((R1 & 7) ^ kg) << 4);
        const int b3_2 = R2 * 512 + (((R2 & 7) ^ kg) << 4);
        const int b3_3 = R3 * 512 + (((R3 & 7) ^ kg) << 4);
        #pragma unroll
        for (int cc = 0; cc < 7; ++cc, ++kidx) {
            bf16x8 a0 = *reinterpret_cast<const bf16x8*>(xsb + (b3_0 ^ (cc << 6)));
            bf16x8 a1 = *reinterpret_cast<const bf16x8*>(xsb + (b3_1 ^ (cc << 6)));
            bf16x8 a2 = *reinterpret_cast<const bf16x8*>(xsb + (b3_2 ^ (cc << 6)));
            bf16x8 a3 = *reinterpret_cast<const bf16x8*>(xsb + (b3_3 ^ (cc << 6)));
            bf16x8 b0 = wp0[kidx * 64];
            bf16x8 b1 = wp1[kidx * 64];
            bf16x8 b2 = wp2[kidx * 64];
            bf16x8 b3 = wp3[kidx * 64];
            bf16x8 b4 = wp4[kidx * 64];
            d00 = __builtin_amdgcn_mfma_f32_16x16x32_bf16(a0, b0, d00, 0, 0, 0);
            d01 = __builtin_amdgcn_mfma_f32_16x16x32_bf16(a1, b0, d01, 0, 0, 0);
            d02 = __builtin_amdgcn_mfma_f32_16x16x32_bf16(a2, b0, d02, 0, 0, 0);
            d03 = __builtin_amdgcn_mfma_f32_16x16x32_bf16(a3, b0, d03, 0, 0, 0);
            d10 = __builtin_amdgcn_mfma_f32_16x16x32_bf16(a0, b1, d10, 0, 0, 0);
            d11 = __builtin_amdgcn_mfma_f32_16x16x32_bf16(a1, b1, d11, 0, 0, 0);
            d12 = __builtin_amdgcn_mfma_f32_16x16x32_bf16(a2, b1, d12, 0, 0, 0);
            d13 = __builtin_amdgcn_mfma_f32_16x16x32_bf16(a3, b1, d13, 0, 0, 0);
            d20 = __builtin_amdgcn_mfma_f32_16x16x32_bf16(a0, b2, d20, 0, 0, 0);
            d21 = __builtin_amdgcn_mfma_f32_16x16x32_bf16(a1, b2, d21, 0, 0, 0);
            d22 = __builtin_amdgcn_mfma_f32_16x16x32_bf16(a2, b2, d22, 0, 0, 0);
            d23 = __builtin_amdgcn_mfma_f32_16x16x32_bf16(a3, b2, d23, 0, 0, 0);
            d30 = __builtin_amdgcn_mfma_f32_16x16x32_bf16(a0, b3, d30, 0, 0, 0);
            d31 = __builtin_amdgcn_mfma_f32_16x16x32_bf16(a1, b3, d31, 0, 0, 0);
            d32 = __builtin_amdgcn_mfma_f32_16x16x32_bf16(a2, b3, d32, 0, 0, 0);
            d33 = __builtin_amdgcn_mfma_f32_16x16x32_bf16(a3, b3, d33, 0, 0, 0);
            d40 = __builtin_amdgcn_mfma_f32_16x16x32_bf16(a0, b4, d40, 0, 0, 0);
            d41 = __builtin_amdgcn_mfma_f32_16x16x32_bf16(a1, b4, d41, 0, 0, 0);
            d42 = __builtin_amdgcn_mfma_f32_16x16x32_bf16(a2, b4, d42, 0, 0, 0);
            d43 = __builtin_amdgcn_mfma_f32_16x16x32_bf16(a3, b4, d43, 0, 0, 0);
        }
    }

#define EPI2B(BL, DM) do {                                                       \
    _Pragma("unroll")                                                            \
    for (int hf = 0; hf < 2; ++hf) {                                             \
        int t0 = 4 * g + 2 * hf;                                                 \
        if (t0 < 12) {                                                           \
            float v0 = LEAKY(DM[2*hf]   + bia);                                  \
            float v1 = LEAKY(DM[2*hf+1] + bia);                                  \
            int rb = (BL) * 18 + t0;                                             \
            if (rs[rb] + rs[rb+1] + rs[rb+2] == 0.f) v0 = 0.f;                   \
            if (rs[rb+1] + rs[rb+2] + rs[rb+3] == 0.f) v1 = 0.f;                 \
            y[((size_t)(4 * blk + (BL)) * 6 + (t0 >> 1)) * C2 + ch] = fmaxf(v0, v1); \
        }                                                                        \
    }                                                                            \
} while (0)

#define EPI2(NTI, DA, DB, DC, DD) do {                                           \
    int ch = (wid + 4 * (NTI)) * 16 + trow;                                      \
    if (ch < C2) {                                                               \
        float bia = bias[ch];                                                    \
        EPI2B(0, DA); EPI2B(1, DB); EPI2B(2, DC); EPI2B(3, DD);                  \
    }                                                                            \
} while (0)

    EPI2(0, d00, d01, d02, d03);
    EPI2(1, d10, d11, d12, d13);
    EPI2(2, d20, d21, d22, d23);
    EPI2(3, d30, d31, d32, d33);
    EPI2(4, d40, d41, d42, d43);
#undef EPI2
#undef EPI2B
}

// ================= conv3: 8 batches/block, wave = 5 nt x 2 group-tiles ==========
__global__ __launch_bounds__(256, 2) void conv3_mfma(
    const float* __restrict__ x, const unsigned short* __restrict__ Wt,
    const float* __restrict__ bias, float* __restrict__ y)
{
    const int b0  = blockIdx.x * 8;
    const int tid = threadIdx.x;
    __shared__ unsigned short xs[48 * 320];
    __shared__ float rs[48];
    char* xsb = reinterpret_cast<char*>(xs);

    for (int idx = tid; idx < 48 * 40; idx += 256) {
        int rg = idx / 40, ck = idx % 40;
        int c0 = ck * 8;
        ushort4 lo = {0,0,0,0}, hi = {0,0,0,0};
        const float* row = x + ((size_t)b0 * 6 + rg) * C2;
        if (c0 + 8 <= C2) {
            const float4* src = reinterpret_cast<const float4*>(row + c0);
            float4 a = src[0], c = src[1];
            lo = ushort4{f2bf(a.x),f2bf(a.y),f2bf(a.z),f2bf(a.w)};
            hi = ushort4{f2bf(c.x),f2bf(c.y),f2bf(c.z),f2bf(c.w)};
        } else if (c0 < C2) {
            unsigned short v[8];
            #pragma unroll
            for (int j = 0; j < 8; ++j)
                v[j] = (c0 + j < C2) ? f2bf(row[c0 + j]) : (unsigned short)0;
            lo = ushort4{v[0],v[1],v[2],v[3]};
            hi = ushort4{v[4],v[5],v[6],v[7]};
        }
        int bo_ = rg * 640 + ((ck ^ (rg & 7)) << 4);
        *reinterpret_cast<ushort4*>(xsb + bo_)     = lo;
        *reinterpret_cast<ushort4*>(xsb + bo_ + 8) = hi;
    }
    __syncthreads();

    const int wid = tid >> 6, lane = tid & 63;
    const int kg = lane >> 4, trow = lane & 15, g = kg;

    for (int r = wid; r < 48; r += 4) {
        float s = 0.f;
        #pragma unroll
        for (int j = 0; j < 5; ++j) {
            int e = lane + 64 * j;
            int chunk = e >> 3, within = e & 7;
            s += bf2f(*reinterpret_cast<unsigned short*>(
                xsb + r * 640 + ((chunk ^ (r & 7)) << 4) + within * 2));
        }
        for (int off = 32; off; off >>= 1) s += __shfl_down(s, off);
        if (lane == 0) rs[r] = s;
    }
    __syncthreads();

    const int rbase = 6 * (trow >> 2) + (trow & 3);

    const bf16x8* wb = reinterpret_cast<const bf16x8*>(Wt);
    const bf16x8* wp0 = wb + (size_t)((wid     ) * KT3) * 64 + lane;
    const bf16x8* wp1 = wb + (size_t)((wid +  4) * KT3) * 64 + lane;
    const bf16x8* wp2 = wb + (size_t)((wid +  8) * KT3) * 64 + lane;
    const bf16x8* wp3 = wb + (size_t)((wid + 12) * KT3) * 64 + lane;
    const bf16x8* wp4 = wb + (size_t)((wid + 16) * KT3) * 64 + lane;

    f32x4 e00={0,0,0,0},e01={0,0,0,0};
    f32x4 e10={0,0,0,0},e11={0,0,0,0};
    f32x4 e20={0,0,0,0},e21={0,0,0,0};
    f32x4 e30={0,0,0,0},e31={0,0,0,0};
    f32x4 e40={0,0,0,0},e41={0,0,0,0};

    int kidx = 0;
    #pragma unroll
    for (int rowoff = 0; rowoff < 3; ++rowoff) {
        #pragma unroll
        for (int cc = 0; cc < 10; ++cc, ++kidx) {
            int chunk = cc * 4 + kg;
            int R0 = rbase + rowoff;
            int R1 = R0 + 24;
            bf16x8 a0 = *reinterpret_cast<const bf16x8*>(xsb + R0*640 + ((chunk ^ (R0 & 7)) << 4));
            bf16x8 a1 = *reinterpret_cast<const bf16x8*>(xsb + R1*640 + ((chunk ^ (R1 & 7)) << 4));
            bf16x8 b0 = wp0[kidx * 64];
            bf16x8 b1 = wp1[kidx * 64];
            bf16x8 b2 = wp2[kidx * 64];
            bf16x8 b3 = wp3[kidx * 64];
            bf16x8 b4 = wp4[kidx * 64];
            e00 = __builtin_amdgcn_mfma_f32_16x16x32_bf16(a0, b0, e00, 0, 0, 0);
            e01 = __builtin_amdgcn_mfma_f32_16x16x32_bf16(a1, b0, e01, 0, 0, 0);
            e10 = __builtin_amdgcn_mfma_f32_16x16x32_bf16(a0, b1, e10, 0, 0, 0);
            e11 = __builtin_amdgcn_mfma_f32_16x16x32_bf16(a1, b1, e11, 0, 0, 0);
            e20 = __builtin_amdgcn_mfma_f32_16x16x32_bf16(a0, b2, e20, 0, 0, 0);
            e21 = __builtin_amdgcn_mfma_f32_16x16x32_bf16(a1, b2, e21, 0, 0, 0);
            e30 = __builtin_amdgcn_mfma_f32_16x16x32_bf16(a0, b3, e30, 0, 0, 0);
            e31 = __builtin_amdgcn_mfma_f32_16x16x32_bf16(a1, b3, e31, 0, 0, 0);
            e40 = __builtin_amdgcn_mfma_f32_16x16x32_bf16(a0, b4, e40, 0, 0, 0);
            e41 = __builtin_amdgcn_mfma_f32_16x16x32_bf16(a1, b4, e41, 0, 0, 0);
        }
    }

#define EPI3G(GR, EM) do {                                                       \
    _Pragma("unroll")                                                            \
    for (int tp = 0; tp < 2; ++tp) {                                             \
        int rb = (GR) * 24 + g * 6 + 2 * tp;                                     \
        float v0 = LEAKY(EM[2*tp]   + bia);                                      \
        float v1 = LEAKY(EM[2*tp+1] + bia);                                      \
        if (rs[rb] + rs[rb+1] + rs[rb+2] == 0.f) v0 = 0.f;                       \
        if (rs[rb+1] + rs[rb+2] + rs[rb+3] == 0.f) v1 = 0.f;                     \
        y[((size_t)(b0 + (GR) * 4 + g) * 2 + tp) * C3 + ch] = fmaxf(v0, v1);     \
    }                                                                            \
} while (0)

#define EPI3(NTI, EA, EB) do {                                                   \
    int ch = (wid + 4 * (NTI)) * 16 + trow;                                      \
    if (ch < C3) {                                                               \
        float bia = bias[ch];                                                    \
        EPI3G(0, EA); EPI3G(1, EB);                                              \
    }                                                                            \
} while (0)

    EPI3(0, e00, e01);
    EPI3(1, e10, e11);
    EPI3(2, e20, e21);
    EPI3(3, e30, e31);
    EPI3(4, e40, e41);
#undef EPI3
#undef EPI3G
}

// ================= feats concat: [y3 | image] -> bf16 [B][2656] =================
__global__ __launch_bounds__(256) void concat_feats(
    const float* __restrict__ y3, const float* __restrict__ img,
    unsigned short* __restrict__ feats)
{
    const int b = blockIdx.x;
    for (int ck = threadIdx.x; ck < FK / 8; ck += 256) {
        int c0 = ck * 8;
        ushort4 lo = {0,0,0,0}, hi = {0,0,0,0};
        const float4* src = nullptr;
        if (c0 + 8 <= 600)       src = reinterpret_cast<const float4*>(y3 + (size_t)b*600 + c0);
        else if (c0 + 8 <= 2648) src = reinterpret_cast<const float4*>(img + (size_t)b*IMG + (c0-600));
        if (src) {
            float4 a = src[0], c = src[1];
            lo = ushort4{f2bf(a.x),f2bf(a.y),f2bf(a.z),f2bf(a.w)};
            hi = ushort4{f2bf(c.x),f2bf(c.y),f2bf(c.z),f2bf(c.w)};
        }
        ushort4* dst = reinterpret_cast<ushort4*>(feats + (size_t)b * FK + c0);
        dst[0] = lo; dst[1] = hi;
    }
}

// ================= final GEMM: 448 blocks x 1 wave, wave = (mt, 4 nts), depth-2 =
__global__ __launch_bounds__(64) void final_mfma(
    const unsigned short* __restrict__ feats, const unsigned short* __restrict__ Wmt,
    const float* __restrict__ bm, float* __restrict__ h)
{
    const int lane = threadIdx.x;
    const int bid  = blockIdx.x;
    const int mt = bid / 7, q = bid % 7;            // 64 mt x 7 q-groups
    const int kg = lane >> 4, trow = lane & 15, g = kg;
    const int m0 = mt * 16;

    const bf16x8* ap = reinterpret_cast<const bf16x8*>(feats)
                       + (size_t)(m0 + trow) * (FK / 8) + kg;
    const bf16x8* wb = reinterpret_cast<const bf16x8*>(Wmt);
    const bf16x8* wp0 = wb + (size_t)((q     ) * KTM) * 64 + lane;
    const bf16x8* wp1 = wb + (size_t)((q +  7) * KTM) * 64 + lane;
    const bf16x8* wp2 = wb + (size_t)((q + 14) * KTM) * 64 + lane;
    const bf16x8* wp3 = wb + (size_t)((q + 21) * KTM) * 64 + lane;

    f32x4 c0 = {0,0,0,0}, c1 = {0,0,0,0}, c2 = {0,0,0,0}, c3 = {0,0,0,0};

    // distance-2 rotate prefetch on A and B
    bf16x8 aA = ap[0],      aB = ap[4];
    bf16x8 b0A = wp0[0],  b1A = wp1[0],  b2A = wp2[0],  b3A = wp3[0];
    bf16x8 b0B = wp0[64], b1B = wp1[64], b2B = wp2[64], b3B = wp3[64];
    for (int kk = 0; kk < KTM - 2; ++kk) {
        bf16x8 a = aA, b0 = b0A, b1 = b1A, b2 = b2A, b3 = b3A;
        aA = aB;  b0A = b0B; b1A = b1B; b2A = b2B; b3A = b3B;
        aB  = ap [(kk + 2) * 4];
        b0B = wp0[(kk + 2) * 64];
        b1B = wp1[(kk + 2) * 64];
        b2B = wp2[(kk + 2) * 64];
        b3B = wp3[(kk + 2) * 64];
        c0 = __builtin_amdgcn_mfma_f32_16x16x32_bf16(a, b0, c0, 0, 0, 0);
        c1 = __builtin_amdgcn_mfma_f32_16x16x32_bf16(a, b1, c1, 0, 0, 0);
        c2 = __builtin_amdgcn_mfma_f32_16x16x32_bf16(a, b2, c2, 0, 0, 0);
        c3 = __builtin_amdgcn_mfma_f32_16x16x32_bf16(a, b3, c3, 0, 0, 0);
    }
    c0 = __builtin_amdgcn_mfma_f32_16x16x32_bf16(aA, b0A, c0, 0, 0, 0);
    c1 = __builtin_amdgcn_mfma_f32_16x16x32_bf16(aA, b1A, c1, 0, 0, 0);
    c2 = __builtin_amdgcn_mfma_f32_16x16x32_bf16(aA, b2A, c2, 0, 0, 0);
    c3 = __builtin_amdgcn_mfma_f32_16x16x32_bf16(aA, b3A, c3, 0, 0, 0);
    c0 = __builtin_amdgcn_mfma_f32_16x16x32_bf16(aB, b0B, c0, 0, 0, 0);
    c1 = __builtin_amdgcn_mfma_f32_16x16x32_bf16(aB, b1B, c1, 0, 0, 0);
    c2 = __builtin_amdgcn_mfma_f32_16x16x32_bf16(aB, b2B, c2, 0, 0, 0);
    c3 = __builtin_amdgcn_mfma_f32_16x16x32_bf16(aB, b3B, c3, 0, 0, 0);

#define EPIM(NT, CM) do {                                                        \
    int ch = (NT) * 16 + trow;                                                   \
    if (ch < LIN2) {                                                             \
        float bia = bm[ch];                                                      \
        _Pragma("unroll")                                                        \
        for (int reg = 0; reg < 4; ++reg) {                                      \
            float v = LEAKY(CM[reg] + bia);                                      \
            h[(size_t)(m0 + 4 * g + reg) * LIN2 + ch] = v;                       \
        }                                                                        \
    }                                                                            \
} while (0)

    EPIM(q,      c0);
    EPIM(q + 7,  c1);
    EPIM(q + 14, c2);
    EPIM(q + 21, c3);
#undef EPIM
}

// ================= out[b] = h[b] . Wo + bo ======================================
__global__ __launch_bounds__(256) void final_reduce(
    const float* __restrict__ h, const float* __restrict__ Wo,
    const float* __restrict__ bo, float* __restrict__ out)
{
    const int tid = threadIdx.x;
    const int wid = tid >> 6, lane = tid & 63;
    const int b = blockIdx.x * 4 + wid;
    float s = 0.f;
    #pragma unroll
    for (int j = 0; j < 7; ++j) {
        int o = lane + 64 * j;
        if (o < LIN2) s += h[(size_t)b * LIN2 + o] * Wo[o];
    }
    for (int off = 32; off; off >>= 1) s += __shfl_down(s, off);
    if (lane == 0) out[b] = s + bo[0];
}

extern "C" void kernel_launch(void* const* d_in, const int* in_sizes, int n_in,
                              void* d_out, int out_size, void* d_ws, size_t ws_size,
                              hipStream_t stream) {
    const float* image = (const float*)d_in[0];
    const int*   sent  = (const int*)  d_in[1];
    const float* emb   = (const float*)d_in[2];
    const float* W1    = (const float*)d_in[3];
    const float* b1    = (const float*)d_in[4];
    const float* W2    = (const float*)d_in[5];
    const float* b2    = (const float*)d_in[6];
    const float* W3    = (const float*)d_in[7];
    const float* b3    = (const float*)d_in[8];
    const float* Wm    = (const float*)d_in[9];
    const float* bm    = (const float*)d_in[10];
    const float* Wo    = (const float*)d_in[11];
    const float* bo    = (const float*)d_in[12];
    float* out = (float*)d_out;

    float* y1 = (float*)d_ws;                          // 2,867,200 f
    float* y2 = y1 + 2867200;                          // 1,843,200 f
    float* y3 = y2 + 1843200;                          //   614,400 f
    unsigned short* W1t = (unsigned short*)(y3 + 614400);   // T1*512
    unsigned short* W2t = W1t + (size_t)T1 * 512;            // T2*512
    unsigned short* W3t = W2t + (size_t)T2 * 512;            // T3*512
    unsigned short* Wmt = W3t + (size_t)T3 * 512;            // TM*512
    unsigned short* feats = (unsigned short*)y1;             // reuse y1 region
    float* h = y2;                                           // reuse y2 region

    convert_all<<<(TTOT * 64 + 255) / 256, 256, 0, stream>>>(
        W1, W2, W3, Wm, W1t, W2t, W3t, Wmt);

    conv1_mfma<<<B_ / 2, 512, 0, stream>>>(sent, emb, W1t, b1, y1);
    conv2_mfma<<<B_ / 4, 256, 0, stream>>>(y1, W2t, b2, y2);
    conv3_mfma<<<B_ / 8, 256, 0, stream>>>(y2, W3t, b3, y3);
    concat_feats<<<B_, 256, 0, stream>>>(y3, image, feats);
    final_mfma<<<64 * 7, 64, 0, stream>>>(feats, Wmt, bm, h);
    final_reduce<<<B_ / 4, 256, 0, stream>>>(h, Wo, bo, out);
}

// Round 9
// 99.039 us; speedup vs baseline: 1.6250x; 1.2663x over previous
//
#include <hip/hip_runtime.h>
#include <hip/hip_bf16.h>

#define LEAKY(v) ((v) > 0.0f ? (v) : 0.01f * (v))

constexpr int B_   = 1024;
constexpr int PAD  = 30;
constexpr int E    = 512;
constexpr int IMG  = 2048;
constexpr int C1   = 200;
constexpr int C2   = 300;
constexpr int C3   = 300;
constexpr int LIN2 = 400;

constexpr int NT1P = 16, KT1 = 48;   // conv1: 256-pad x 1536
constexpr int NT2P = 20, KT2 = 21;   // conv2: 320-pad x (3x7 steps in 256-pad rows)
constexpr int NT3P = 24, KT3 = 30;   // conv3: 384-pad x (3x10 steps in 320-pad rows)
constexpr int NTMP = 28, KTM = 83;   // final: 448-pad x 2656
constexpr int FK  = 2656;            // feats K padded (2648 -> 2656)

constexpr int T1 = NT1P * KT1;       // 768
constexpr int T2 = NT2P * KT2;       // 420
constexpr int T3 = NT3P * KT3;       // 720
constexpr int TM = NTMP * KTM;       // 2324
constexpr int TTOT = T1 + T2 + T3 + TM;  // 4232

typedef __attribute__((ext_vector_type(8))) short bf16x8;
typedef __attribute__((ext_vector_type(4))) float f32x4;

__device__ inline unsigned short f2bf(float f) {
    __hip_bfloat16 h = __float2bfloat16(f);
    return *reinterpret_cast<unsigned short*>(&h);
}
__device__ inline float bf2f(unsigned short u) {
    unsigned int b = ((unsigned int)u) << 16;
    return __uint_as_float(b);
}

// ================= fused weight converter: fp32 -> bf16 fragments [nt][kk][lane][8]
__global__ __launch_bounds__(256) void convert_all(
    const float* __restrict__ W1, const float* __restrict__ W2,
    const float* __restrict__ W3, const float* __restrict__ Wm,
    unsigned short* __restrict__ W1t, unsigned short* __restrict__ W2t,
    unsigned short* __restrict__ W3t, unsigned short* __restrict__ Wmt)
{
    int idx = blockIdx.x * 256 + threadIdx.x;
    if (idx >= TTOT * 64) return;
    int lane = idx & 63, t = idx >> 6;
    unsigned short v[8];

    if (t < T1) {
        int kk = t % KT1, nt = t / KT1;
        int ch = nt * 16 + (lane & 15);
        int k0 = kk * 32 + (lane >> 4) * 8;
        #pragma unroll
        for (int j = 0; j < 8; ++j)
            v[j] = (ch < C1) ? f2bf(W1[(size_t)ch * (3*E) + k0 + j]) : (unsigned short)0;
        ushort4* dst = reinterpret_cast<ushort4*>(W1t) + (size_t)t * 128 + lane * 2;
        dst[0] = ushort4{v[0],v[1],v[2],v[3]};
        dst[1] = ushort4{v[4],v[5],v[6],v[7]};
    } else if (t < T1 + T2) {
        int tt = t - T1;
        int kk = tt % KT2, nt = tt / KT2;
        int ch = nt * 16 + (lane & 15);
        int rowoff = kk / 7;
        int cbase  = (kk % 7) * 32 + (lane >> 4) * 8;
        #pragma unroll
        for (int j = 0; j < 8; ++j) {
            int c = cbase + j;
            v[j] = (ch < C2 && c < C1) ? f2bf(W2[(size_t)ch * (3*C1) + rowoff * C1 + c])
                                       : (unsigned short)0;
        }
        ushort4* dst = reinterpret_cast<ushort4*>(W2t) + (size_t)tt * 128 + lane * 2;
        dst[0] = ushort4{v[0],v[1],v[2],v[3]};
        dst[1] = ushort4{v[4],v[5],v[6],v[7]};
    } else if (t < T1 + T2 + T3) {
        int tt = t - T1 - T2;
        int kk = tt % KT3, nt = tt / KT3;
        int ch = nt * 16 + (lane & 15);
        int rowoff = kk / 10;
        int cbase  = (kk % 10) * 32 + (lane >> 4) * 8;
        #pragma unroll
        for (int j = 0; j < 8; ++j) {
            int c = cbase + j;
            v[j] = (ch < C3 && c < C2) ? f2bf(W3[(size_t)ch * (3*C2) + rowoff * C2 + c])
                                       : (unsigned short)0;
        }
        ushort4* dst = reinterpret_cast<ushort4*>(W3t) + (size_t)tt * 128 + lane * 2;
        dst[0] = ushort4{v[0],v[1],v[2],v[3]};
        dst[1] = ushort4{v[4],v[5],v[6],v[7]};
    } else {
        int tt = t - T1 - T2 - T3;
        int kk = tt % KTM, nt = tt / KTM;
        int ch = nt * 16 + (lane & 15);
        int kbase = kk * 32 + (lane >> 4) * 8;
        #pragma unroll
        for (int j = 0; j < 8; ++j) {
            int k = kbase + j;
            v[j] = (ch < LIN2 && k < 2648) ? f2bf(Wm[(size_t)ch * 2648 + k])
                                           : (unsigned short)0;
        }
        ushort4* dst = reinterpret_cast<ushort4*>(Wmt) + (size_t)tt * 128 + lane * 2;
        dst[0] = ushort4{v[0],v[1],v[2],v[3]};
        dst[1] = ushort4{v[4],v[5],v[6],v[7]};
    }
}

// ================= conv1: 2 batches/block, 512 thr (8 waves), wave = 2 nt x 4 M ==
// (unchanged from round 8 — verified)
__global__ __launch_bounds__(512, 4) void conv1_mfma(
    const int* __restrict__ sent, const float* __restrict__ emb,
    const unsigned short* __restrict__ W1t, const float* __restrict__ bias,
    float* __restrict__ y)
{
    const int blk = blockIdx.x;            // batches 2*blk, 2*blk+1
    const int tid = threadIdx.x;
    __shared__ unsigned short xs[66 * 512];
    __shared__ float rs[64];
    char* xsb = reinterpret_cast<char*>(xs);

    const int wid = tid >> 6, lane = tid & 63;    // wid 0..7

    for (int r = wid; r < 60; r += 8) {
        int bl = r / 30, rr = r % 30;
        int R = bl * 32 + rr;
        int row = sent[(2 * blk + bl) * PAD + rr];
        const float4* src = reinterpret_cast<const float4*>(emb + (size_t)row * E) + lane * 2;
        float4 e0 = src[0], e1 = src[1];
        float sum = e0.x + e0.y + e0.z + e0.w + e1.x + e1.y + e1.z + e1.w;
        union { ushort4 u4[2]; bf16x8 v; } pk;
        pk.u4[0] = ushort4{f2bf(e0.x), f2bf(e0.y), f2bf(e0.z), f2bf(e0.w)};
        pk.u4[1] = ushort4{f2bf(e1.x), f2bf(e1.y), f2bf(e1.z), f2bf(e1.w)};
        int byteoff = R * 1024 + ((lane ^ (R & 7)) << 4);
        *reinterpret_cast<bf16x8*>(xsb + byteoff) = pk.v;
        for (int off = 32; off; off >>= 1) sum += __shfl_down(sum, off);
        if (lane == 0) rs[R] = sum;
    }
    if (tid < 384) {
        int zi = tid >> 6;
        int R = (zi < 2) ? (30 + zi) : (60 + zi);
        int byteoff = R * 1024 + ((lane ^ (R & 7)) << 4);
        union { ushort4 u4[2]; bf16x8 v; } pk;
        pk.u4[0] = ushort4{0,0,0,0}; pk.u4[1] = ushort4{0,0,0,0};
        *reinterpret_cast<bf16x8*>(xsb + byteoff) = pk.v;
    }
    if (tid < 4) {
        const int pr[4] = {30, 31, 62, 63};
        rs[pr[tid]] = 0.f;
    }
    __syncthreads();

    const int kg = lane >> 4, trow = lane & 15, g = kg;

    const bf16x8* wb = reinterpret_cast<const bf16x8*>(W1t);
    const bf16x8* wp0 = wb + (size_t)((wid    ) * KT1) * 64 + lane;
    const bf16x8* wp1 = wb + (size_t)((wid + 8) * KT1) * 64 + lane;

    f32x4 c00={0,0,0,0},c01={0,0,0,0},c02={0,0,0,0},c03={0,0,0,0};
    f32x4 c10={0,0,0,0},c11={0,0,0,0},c12={0,0,0,0},c13={0,0,0,0};

    #pragma unroll
    for (int rowoff = 0; rowoff < 3; ++rowoff) {
        const int R0 = trow + rowoff;
        const int R1 = R0 + 16, R2 = R0 + 32, R3 = R0 + 48;
        const int b3_0 = R0 * 1024 + (((R0 & 7) ^ kg) << 4);
        const int b3_1 = R1 * 1024 + (((R1 & 7) ^ kg) << 4);
        const int b3_2 = R2 * 1024 + (((R2 & 7) ^ kg) << 4);
        const int b3_3 = R3 * 1024 + (((R3 & 7) ^ kg) << 4);
        #pragma unroll
        for (int cc = 0; cc < 16; ++cc) {
            const int kk = rowoff * 16 + cc;
            bf16x8 a0 = *reinterpret_cast<const bf16x8*>(xsb + (b3_0 ^ (cc << 6)));
            bf16x8 a1 = *reinterpret_cast<const bf16x8*>(xsb + (b3_1 ^ (cc << 6)));
            bf16x8 a2 = *reinterpret_cast<const bf16x8*>(xsb + (b3_2 ^ (cc << 6)));
            bf16x8 a3 = *reinterpret_cast<const bf16x8*>(xsb + (b3_3 ^ (cc << 6)));
            bf16x8 b0 = wp0[kk * 64];
            bf16x8 b1 = wp1[kk * 64];
            c00 = __builtin_amdgcn_mfma_f32_16x16x32_bf16(a0, b0, c00, 0, 0, 0);
            c01 = __builtin_amdgcn_mfma_f32_16x16x32_bf16(a1, b0, c01, 0, 0, 0);
            c02 = __builtin_amdgcn_mfma_f32_16x16x32_bf16(a2, b0, c02, 0, 0, 0);
            c03 = __builtin_amdgcn_mfma_f32_16x16x32_bf16(a3, b0, c03, 0, 0, 0);
            c10 = __builtin_amdgcn_mfma_f32_16x16x32_bf16(a0, b1, c10, 0, 0, 0);
            c11 = __builtin_amdgcn_mfma_f32_16x16x32_bf16(a1, b1, c11, 0, 0, 0);
            c12 = __builtin_amdgcn_mfma_f32_16x16x32_bf16(a2, b1, c12, 0, 0, 0);
            c13 = __builtin_amdgcn_mfma_f32_16x16x32_bf16(a3, b1, c13, 0, 0, 0);
        }
    }

#define EPIM1(MT, CM) do {                                                       \
    int bl = (MT) >> 1;                                                          \
    int mloc = ((MT) & 1) * 16;                                                  \
    int bb = 2 * blk + bl;                                                       \
    _Pragma("unroll")                                                            \
    for (int hf = 0; hf < 2; ++hf) {                                             \
        int wl = mloc + 4 * g + 2 * hf;                                          \
        int tp = wl >> 1;                                                        \
        if (tp < 14) {                                                           \
            float v0 = CM[2*hf] + bia, v1 = CM[2*hf+1] + bia;                    \
            v0 = LEAKY(v0); v1 = LEAKY(v1);                                      \
            int rb = bl * 32 + wl;                                               \
            if (rs[rb] + rs[rb+1] + rs[rb+2] == 0.f) v0 = 0.f;                   \
            if (rs[rb+1] + rs[rb+2] + rs[rb+3] == 0.f) v1 = 0.f;                 \
            y[(size_t)(bb * 14 + tp) * C1 + ch] = fmaxf(v0, v1);                 \
        }                                                                        \
    }                                                                            \
} while (0)

#define EPI1(NTI, CA, CB, CC, CD) do {                                           \
    int ch = (wid + 8 * (NTI)) * 16 + trow;                                      \
    if (ch < C1) {                                                               \
        float bia = bias[ch];                                                    \
        EPIM1(0, CA); EPIM1(1, CB); EPIM1(2, CC); EPIM1(3, CD);                  \
    }                                                                            \
} while (0)

    EPI1(0, c00, c01, c02, c03);
    EPI1(1, c10, c11, c12, c13);
#undef EPI1
#undef EPIM1
}

// ================= conv2: 1 batch/block (grid 1024), 4 waves x 5 nt =============
// LDS 18 rows x 256 bf16 swizzled (9 KB). 16 waves/CU target.
__global__ __launch_bounds__(256, 4) void conv2_mfma(
    const float* __restrict__ x, const unsigned short* __restrict__ Wt,
    const float* __restrict__ bias, float* __restrict__ y)
{
    const int b   = blockIdx.x;
    const int tid = threadIdx.x;
    __shared__ unsigned short xs[18 * 256];
    __shared__ float rs[18];
    char* xsb = reinterpret_cast<char*>(xs);

    for (int idx = tid; idx < 18 * 32; idx += 256) {
        int r = idx >> 5, ck = idx & 31;
        ushort4 lo = {0,0,0,0}, hi = {0,0,0,0};
        if (r < 14 && ck < 25) {
            const float4* src = reinterpret_cast<const float4*>(
                x + ((size_t)b * 14 + r) * C1 + ck * 8);
            float4 a = src[0], c = src[1];
            lo = ushort4{f2bf(a.x),f2bf(a.y),f2bf(a.z),f2bf(a.w)};
            hi = ushort4{f2bf(c.x),f2bf(c.y),f2bf(c.z),f2bf(c.w)};
        }
        int bo_ = r * 512 + ((ck ^ (r & 7)) << 4);
        *reinterpret_cast<ushort4*>(xsb + bo_)     = lo;
        *reinterpret_cast<ushort4*>(xsb + bo_ + 8) = hi;
    }
    __syncthreads();

    const int wid = tid >> 6, lane = tid & 63;
    const int kg = lane >> 4, trow = lane & 15, g = kg;

    for (int r = wid; r < 18; r += 4) {
        float s = 0.f;
        #pragma unroll
        for (int j = 0; j < 4; ++j) {
            int e = lane + 64 * j;
            int chunk = e >> 3, within = e & 7;
            s += bf2f(*reinterpret_cast<unsigned short*>(
                xsb + r * 512 + ((chunk ^ (r & 7)) << 4) + within * 2));
        }
        for (int off = 32; off; off >>= 1) s += __shfl_down(s, off);
        if (lane == 0) rs[r] = s;
    }
    __syncthreads();

    const bf16x8* wb = reinterpret_cast<const bf16x8*>(Wt);
    const bf16x8* wp0 = wb + (size_t)((wid     ) * KT2) * 64 + lane;
    const bf16x8* wp1 = wb + (size_t)((wid +  4) * KT2) * 64 + lane;
    const bf16x8* wp2 = wb + (size_t)((wid +  8) * KT2) * 64 + lane;
    const bf16x8* wp3 = wb + (size_t)((wid + 12) * KT2) * 64 + lane;
    const bf16x8* wp4 = wb + (size_t)((wid + 16) * KT2) * 64 + lane;

    f32x4 d0={0,0,0,0},d1={0,0,0,0},d2={0,0,0,0},d3={0,0,0,0},d4={0,0,0,0};

    int kidx = 0;
    #pragma unroll
    for (int rowoff = 0; rowoff < 3; ++rowoff) {
        const int R0 = trow + rowoff;
        const int b3 = R0 * 512 + (((R0 & 7) ^ kg) << 4);
        #pragma unroll
        for (int cc = 0; cc < 7; ++cc, ++kidx) {
            bf16x8 a0 = *reinterpret_cast<const bf16x8*>(xsb + (b3 ^ (cc << 6)));
            bf16x8 b0 = wp0[kidx * 64];
            bf16x8 b1 = wp1[kidx * 64];
            bf16x8 b2 = wp2[kidx * 64];
            bf16x8 b3v = wp3[kidx * 64];
            bf16x8 b4 = wp4[kidx * 64];
            d0 = __builtin_amdgcn_mfma_f32_16x16x32_bf16(a0, b0,  d0, 0, 0, 0);
            d1 = __builtin_amdgcn_mfma_f32_16x16x32_bf16(a0, b1,  d1, 0, 0, 0);
            d2 = __builtin_amdgcn_mfma_f32_16x16x32_bf16(a0, b2,  d2, 0, 0, 0);
            d3 = __builtin_amdgcn_mfma_f32_16x16x32_bf16(a0, b3v, d3, 0, 0, 0);
            d4 = __builtin_amdgcn_mfma_f32_16x16x32_bf16(a0, b4,  d4, 0, 0, 0);
        }
    }

#define EPI2(NTI, DM) do {                                                       \
    int ch = (wid + 4 * (NTI)) * 16 + trow;                                      \
    if (ch < C2) {                                                               \
        float bia = bias[ch];                                                    \
        _Pragma("unroll")                                                        \
        for (int hf = 0; hf < 2; ++hf) {                                         \
            int t0 = 4 * g + 2 * hf;                                             \
            if (t0 < 12) {                                                       \
                float v0 = LEAKY(DM[2*hf]   + bia);                              \
                float v1 = LEAKY(DM[2*hf+1] + bia);                              \
                if (rs[t0] + rs[t0+1] + rs[t0+2] == 0.f) v0 = 0.f;               \
                if (rs[t0+1] + rs[t0+2] + rs[t0+3] == 0.f) v1 = 0.f;             \
                y[((size_t)b * 6 + (t0 >> 1)) * C2 + ch] = fmaxf(v0, v1);        \
            }                                                                    \
        }                                                                        \
    }                                                                            \
} while (0)

    EPI2(0, d0);
    EPI2(1, d1);
    EPI2(2, d2);
    EPI2(3, d3);
    EPI2(4, d4);
#undef EPI2
}

// ================= conv3: 4 batches/block, 512 thr (8 waves x 3 nt, NT pad 24) ==
// LDS 24 rows x 320 bf16 (15 KB), all rows real (4 batches x 6 rows).
__global__ __launch_bounds__(512, 4) void conv3_mfma(
    const float* __restrict__ x, const unsigned short* __restrict__ Wt,
    const float* __restrict__ bias, float* __restrict__ y)
{
    const int b0  = blockIdx.x * 4;
    const int tid = threadIdx.x;
    __shared__ unsigned short xs[24 * 320];
    __shared__ float rs[24];
    char* xsb = reinterpret_cast<char*>(xs);

    for (int idx = tid; idx < 24 * 40; idx += 512) {
        int rg = idx / 40, ck = idx % 40;
        int c0 = ck * 8;
        ushort4 lo = {0,0,0,0}, hi = {0,0,0,0};
        const float* row = x + ((size_t)b0 * 6 + rg) * C2;
        if (c0 + 8 <= C2) {
            const float4* src = reinterpret_cast<const float4*>(row + c0);
            float4 a = src[0], c = src[1];
            lo = ushort4{f2bf(a.x),f2bf(a.y),f2bf(a.z),f2bf(a.w)};
            hi = ushort4{f2bf(c.x),f2bf(c.y),f2bf(c.z),f2bf(c.w)};
        } else if (c0 < C2) {
            unsigned short v[8];
            #pragma unroll
            for (int j = 0; j < 8; ++j)
                v[j] = (c0 + j < C2) ? f2bf(row[c0 + j]) : (unsigned short)0;
            lo = ushort4{v[0],v[1],v[2],v[3]};
            hi = ushort4{v[4],v[5],v[6],v[7]};
        }
        int bo_ = rg * 640 + ((ck ^ (rg & 7)) << 4);
        *reinterpret_cast<ushort4*>(xsb + bo_)     = lo;
        *reinterpret_cast<ushort4*>(xsb + bo_ + 8) = hi;
    }
    __syncthreads();

    const int wid = tid >> 6, lane = tid & 63;   // wid 0..7
    const int kg = lane >> 4, trow = lane & 15, g = kg;

    for (int r = wid; r < 24; r += 8) {
        float s = 0.f;
        #pragma unroll
        for (int j = 0; j < 5; ++j) {
            int e = lane + 64 * j;
            int chunk = e >> 3, within = e & 7;
            s += bf2f(*reinterpret_cast<unsigned short*>(
                xsb + r * 640 + ((chunk ^ (r & 7)) << 4) + within * 2));
        }
        for (int off = 32; off; off >>= 1) s += __shfl_down(s, off);
        if (lane == 0) rs[r] = s;
    }
    __syncthreads();

    const int rbase = 6 * (trow >> 2) + (trow & 3);

    const bf16x8* wb = reinterpret_cast<const bf16x8*>(Wt);
    const bf16x8* wp0 = wb + (size_t)((wid     ) * KT3) * 64 + lane;
    const bf16x8* wp1 = wb + (size_t)((wid +  8) * KT3) * 64 + lane;
    const bf16x8* wp2 = wb + (size_t)((wid + 16) * KT3) * 64 + lane;

    f32x4 e0={0,0,0,0},e1={0,0,0,0},e2={0,0,0,0};

    int kidx = 0;
    #pragma unroll
    for (int rowoff = 0; rowoff < 3; ++rowoff) {
        const int R0 = rbase + rowoff;
        #pragma unroll
        for (int cc = 0; cc < 10; ++cc, ++kidx) {
            int chunk = cc * 4 + kg;
            bf16x8 a0 = *reinterpret_cast<const bf16x8*>(
                xsb + R0 * 640 + ((chunk ^ (R0 & 7)) << 4));
            bf16x8 b0 = wp0[kidx * 64];
            bf16x8 b1 = wp1[kidx * 64];
            bf16x8 b2 = wp2[kidx * 64];
            e0 = __builtin_amdgcn_mfma_f32_16x16x32_bf16(a0, b0, e0, 0, 0, 0);
            e1 = __builtin_amdgcn_mfma_f32_16x16x32_bf16(a0, b1, e1, 0, 0, 0);
            e2 = __builtin_amdgcn_mfma_f32_16x16x32_bf16(a0, b2, e2, 0, 0, 0);
        }
    }

#define EPI3(NTI, EM) do {                                                       \
    int ch = (wid + 8 * (NTI)) * 16 + trow;                                      \
    if (ch < C3) {                                                               \
        float bia = bias[ch];                                                    \
        _Pragma("unroll")                                                        \
        for (int tp = 0; tp < 2; ++tp) {                                         \
            int rb = g * 6 + 2 * tp;                                             \
            float v0 = LEAKY(EM[2*tp]   + bia);                                  \
            float v1 = LEAKY(EM[2*tp+1] + bia);                                  \
            if (rs[rb] + rs[rb+1] + rs[rb+2] == 0.f) v0 = 0.f;                   \
            if (rs[rb+1] + rs[rb+2] + rs[rb+3] == 0.f) v1 = 0.f;                 \
            y[((size_t)(b0 + g) * 2 + tp) * C3 + ch] = fmaxf(v0, v1);            \
        }                                                                        \
    }                                                                            \
} while (0)

    EPI3(0, e0);
    EPI3(1, e1);
    EPI3(2, e2);
#undef EPI3
}

// ================= feats concat: [y3 | image] -> bf16 [B][2656] =================
__global__ __launch_bounds__(256) void concat_feats(
    const float* __restrict__ y3, const float* __restrict__ img,
    unsigned short* __restrict__ feats)
{
    const int b = blockIdx.x;
    for (int ck = threadIdx.x; ck < FK / 8; ck += 256) {
        int c0 = ck * 8;
        ushort4 lo = {0,0,0,0}, hi = {0,0,0,0};
        const float4* src = nullptr;
        if (c0 + 8 <= 600)       src = reinterpret_cast<const float4*>(y3 + (size_t)b*600 + c0);
        else if (c0 + 8 <= 2648) src = reinterpret_cast<const float4*>(img + (size_t)b*IMG + (c0-600));
        if (src) {
            float4 a = src[0], c = src[1];
            lo = ushort4{f2bf(a.x),f2bf(a.y),f2bf(a.z),f2bf(a.w)};
            hi = ushort4{f2bf(c.x),f2bf(c.y),f2bf(c.z),f2bf(c.w)};
        }
        ushort4* dst = reinterpret_cast<ushort4*>(feats + (size_t)b * FK + c0);
        dst[0] = lo; dst[1] = hi;
    }
}

// ================= final GEMM: 448 blocks x 1 wave, wave = (mt, 4 nts), depth-2 =
__global__ __launch_bounds__(64) void final_mfma(
    const unsigned short* __restrict__ feats, const unsigned short* __restrict__ Wmt,
    const float* __restrict__ bm, float* __restrict__ h)
{
    const int lane = threadIdx.x;
    const int bid  = blockIdx.x;
    const int mt = bid / 7, q = bid % 7;
    const int kg = lane >> 4, trow = lane & 15, g = kg;
    const int m0 = mt * 16;

    const bf16x8* ap = reinterpret_cast<const bf16x8*>(feats)
                       + (size_t)(m0 + trow) * (FK / 8) + kg;
    const bf16x8* wb = reinterpret_cast<const bf16x8*>(Wmt);
    const bf16x8* wp0 = wb + (size_t)((q     ) * KTM) * 64 + lane;
    const bf16x8* wp1 = wb + (size_t)((q +  7) * KTM) * 64 + lane;
    const bf16x8* wp2 = wb + (size_t)((q + 14) * KTM) * 64 + lane;
    const bf16x8* wp3 = wb + (size_t)((q + 21) * KTM) * 64 + lane;

    f32x4 c0 = {0,0,0,0}, c1 = {0,0,0,0}, c2 = {0,0,0,0}, c3 = {0,0,0,0};

    bf16x8 aA = ap[0],      aB = ap[4];
    bf16x8 b0A = wp0[0],  b1A = wp1[0],  b2A = wp2[0],  b3A = wp3[0];
    bf16x8 b0B = wp0[64], b1B = wp1[64], b2B = wp2[64], b3B = wp3[64];
    for (int kk = 0; kk < KTM - 2; ++kk) {
        bf16x8 a = aA, b0 = b0A, b1 = b1A, b2 = b2A, b3 = b3A;
        aA = aB;  b0A = b0B; b1A = b1B; b2A = b2B; b3A = b3B;
        aB  = ap [(kk + 2) * 4];
        b0B = wp0[(kk + 2) * 64];
        b1B = wp1[(kk + 2) * 64];
        b2B = wp2[(kk + 2) * 64];
        b3B = wp3[(kk + 2) * 64];
        c0 = __builtin_amdgcn_mfma_f32_16x16x32_bf16(a, b0, c0, 0, 0, 0);
        c1 = __builtin_amdgcn_mfma_f32_16x16x32_bf16(a, b1, c1, 0, 0, 0);
        c2 = __builtin_amdgcn_mfma_f32_16x16x32_bf16(a, b2, c2, 0, 0, 0);
        c3 = __builtin_amdgcn_mfma_f32_16x16x32_bf16(a, b3, c3, 0, 0, 0);
    }
    c0 = __builtin_amdgcn_mfma_f32_16x16x32_bf16(aA, b0A, c0, 0, 0, 0);
    c1 = __builtin_amdgcn_mfma_f32_16x16x32_bf16(aA, b1A, c1, 0, 0, 0);
    c2 = __builtin_amdgcn_mfma_f32_16x16x32_bf16(aA, b2A, c2, 0, 0, 0);
    c3 = __builtin_amdgcn_mfma_f32_16x16x32_bf16(aA, b3A, c3, 0, 0, 0);
    c0 = __builtin_amdgcn_mfma_f32_16x16x32_bf16(aB, b0B, c0, 0, 0, 0);
    c1 = __builtin_amdgcn_mfma_f32_16x16x32_bf16(aB, b1B, c1, 0, 0, 0);
    c2 = __builtin_amdgcn_mfma_f32_16x16x32_bf16(aB, b2B, c2, 0, 0, 0);
    c3 = __builtin_amdgcn_mfma_f32_16x16x32_bf16(aB, b3B, c3, 0, 0, 0);

#define EPIM(NT, CM) do {                                                        \
    int ch = (NT) * 16 + trow;                                                   \
    if (ch < LIN2) {                                                             \
        float bia = bm[ch];                                                      \
        _Pragma("unroll")                                                        \
        for (int reg = 0; reg < 4; ++reg) {                                      \
            float v = LEAKY(CM[reg] + bia);                                      \
            h[(size_t)(m0 + 4 * g + reg) * LIN2 + ch] = v;                       \
        }                                                                        \
    }                                                                            \
} while (0)

    EPIM(q,      c0);
    EPIM(q + 7,  c1);
    EPIM(q + 14, c2);
    EPIM(q + 21, c3);
#undef EPIM
}

// ================= out[b] = h[b] . Wo + bo ======================================
__global__ __launch_bounds__(256) void final_reduce(
    const float* __restrict__ h, const float* __restrict__ Wo,
    const float* __restrict__ bo, float* __restrict__ out)
{
    const int tid = threadIdx.x;
    const int wid = tid >> 6, lane = tid & 63;
    const int b = blockIdx.x * 4 + wid;
    float s = 0.f;
    #pragma unroll
    for (int j = 0; j < 7; ++j) {
        int o = lane + 64 * j;
        if (o < LIN2) s += h[(size_t)b * LIN2 + o] * Wo[o];
    }
    for (int off = 32; off; off >>= 1) s += __shfl_down(s, off);
    if (lane == 0) out[b] = s + bo[0];
}

extern "C" void kernel_launch(void* const* d_in, const int* in_sizes, int n_in,
                              void* d_out, int out_size, void* d_ws, size_t ws_size,
                              hipStream_t stream) {
    const float* image = (const float*)d_in[0];
    const int*   sent  = (const int*)  d_in[1];
    const float* emb   = (const float*)d_in[2];
    const float* W1    = (const float*)d_in[3];
    const float* b1    = (const float*)d_in[4];
    const float* W2    = (const float*)d_in[5];
    const float* b2    = (const float*)d_in[6];
    const float* W3    = (const float*)d_in[7];
    const float* b3    = (const float*)d_in[8];
    const float* Wm    = (const float*)d_in[9];
    const float* bm    = (const float*)d_in[10];
    const float* Wo    = (const float*)d_in[11];
    const float* bo    = (const float*)d_in[12];
    float* out = (float*)d_out;

    float* y1 = (float*)d_ws;                          // 2,867,200 f
    float* y2 = y1 + 2867200;                          // 1,843,200 f
    float* y3 = y2 + 1843200;                          //   614,400 f
    unsigned short* W1t = (unsigned short*)(y3 + 614400);   // T1*512
    unsigned short* W2t = W1t + (size_t)T1 * 512;            // T2*512
    unsigned short* W3t = W2t + (size_t)T2 * 512;            // T3*512
    unsigned short* Wmt = W3t + (size_t)T3 * 512;            // TM*512
    unsigned short* feats = (unsigned short*)y1;             // reuse y1 region
    float* h = y2;                                           // reuse y2 region

    convert_all<<<(TTOT * 64 + 255) / 256, 256, 0, stream>>>(
        W1, W2, W3, Wm, W1t, W2t, W3t, Wmt);

    conv1_mfma<<<B_ / 2, 512, 0, stream>>>(sent, emb, W1t, b1, y1);
    conv2_mfma<<<B_, 256, 0, stream>>>(y1, W2t, b2, y2);
    conv3_mfma<<<B_ / 4, 512, 0, stream>>>(y2, W3t, b3, y3);
    concat_feats<<<B_, 256, 0, stream>>>(y3, image, feats);
    final_mfma<<<64 * 7, 64, 0, stream>>>(feats, Wmt, bm, h);
    final_reduce<<<B_ / 4, 256, 0, stream>>>(h, Wo, bo, out);
}